// Round 1
// baseline (324.179 us; speedup 1.0000x reference)
//
#include <hip/hip_runtime.h>
#include <hip/hip_bf16.h>

using bf16 = __hip_bfloat16;
typedef __attribute__((ext_vector_type(8))) short short8;   // 8 bf16 = 4 VGPRs
typedef __attribute__((ext_vector_type(4))) float floatx4;  // 4 fp32 acc

// async global->LDS, 16B per lane, dest = wave-uniform base + lane*16
__device__ __forceinline__ void async_ld16(const bf16* g, bf16* l) {
  __builtin_amdgcn_global_load_lds((const __attribute__((address_space(1))) void*)g,
                                   (__attribute__((address_space(3))) void*)l, 16, 0, 0);
}

// Core 128x128-tile bt-GEMM: C[128,128] = A[128,K] * B[128,K]^T, bf16 in, fp32 acc.
// Block = 256 threads = 4 waves in 2x2; each wave owns a 64x64 subtile (4x4 MFMAs).
__device__ __forceinline__ void gemm_core(const bf16* __restrict__ At,
                                          const bf16* __restrict__ Bt,
                                          int K, bf16* lA, bf16* lB,
                                          floatx4 acc[4][4]) {
  const int tid  = threadIdx.x;
  const int w    = tid >> 6;
  const int lane = tid & 63;
  const int subM = (w >> 1) * 64;
  const int subN = (w & 1) * 64;
  const int fr   = lane & 15;
  const int fq   = lane >> 4;

  // staging geometry: tile = 128 rows x 32 cols bf16 = 512 chunks of 16B
  const int c0 = w * 64 + lane;
  const int r0 = c0 >> 2, o0 = (c0 & 3) * 8;
  const int c1 = 256 + c0;
  const int r1 = c1 >> 2, o1 = (c1 & 3) * 8;

  floatx4 zero = {0.f, 0.f, 0.f, 0.f};
#pragma unroll
  for (int i = 0; i < 4; ++i)
#pragma unroll
    for (int j = 0; j < 4; ++j) acc[i][j] = zero;

  for (int k0 = 0; k0 < K; k0 += 32) {
    __syncthreads();
    async_ld16(At + (size_t)r0 * K + k0 + o0, lA + (size_t)(w * 64) * 8);
    async_ld16(Bt + (size_t)r0 * K + k0 + o0, lB + (size_t)(w * 64) * 8);
    async_ld16(At + (size_t)r1 * K + k0 + o1, lA + (size_t)(256 + w * 64) * 8);
    async_ld16(Bt + (size_t)r1 * K + k0 + o1, lB + (size_t)(256 + w * 64) * 8);
    __syncthreads();  // compiler drains vmcnt before s_barrier

    short8 a[4], b[4];
#pragma unroll
    for (int i = 0; i < 4; ++i)
      a[i] = *(const short8*)(lA + (subM + i * 16 + fr) * 32 + fq * 8);
#pragma unroll
    for (int j = 0; j < 4; ++j)
      b[j] = *(const short8*)(lB + (subN + j * 16 + fr) * 32 + fq * 8);
#pragma unroll
    for (int i = 0; i < 4; ++i)
#pragma unroll
      for (int j = 0; j < 4; ++j)
        acc[i][j] = __builtin_amdgcn_mfma_f32_16x16x32_bf16(a[i], b[j], acc[i][j], 0, 0, 0);
  }
}

// ---- QKV projection: C = Xbf[8192,1024] * W[z][1024,1024]^T ----
__global__ __launch_bounds__(256) void qkv_gemm(const bf16* __restrict__ Xbf,
                                                const bf16* __restrict__ Wbf,
                                                bf16* __restrict__ Qbf,
                                                bf16* __restrict__ Kbf,
                                                bf16* __restrict__ Vt,
                                                float* __restrict__ Vsd) {
  __shared__ bf16 lA[128 * 32];
  __shared__ bf16 lB[128 * 32];
  const int z = blockIdx.z;
  const bf16* At = Xbf + (size_t)blockIdx.y * 128 * 1024;
  const bf16* Bt = Wbf + (size_t)z * 1024 * 1024 + (size_t)blockIdx.x * 128 * 1024;
  floatx4 acc[4][4];
  gemm_core(At, Bt, 1024, lA, lB, acc);

  const int tid = threadIdx.x, w = tid >> 6, lane = tid & 63;
  const int subM = (w >> 1) * 64, subN = (w & 1) * 64;
  const int fr = lane & 15, fq = lane >> 4;
  const int rowBase = blockIdx.y * 128 + subM;
  const int colBase = blockIdx.x * 128 + subN;
#pragma unroll
  for (int i = 0; i < 4; ++i)
#pragma unroll
    for (int j = 0; j < 4; ++j)
#pragma unroll
      for (int r = 0; r < 4; ++r) {
        int row = rowBase + i * 16 + fq * 4 + r;
        int col = colBase + j * 16 + fr;
        float vv = acc[i][j][r];
        if (z == 0) {
          Qbf[(size_t)row * 1024 + col] = __float2bfloat16(vv);
        } else if (z == 1) {
          Kbf[(size_t)row * 1024 + col] = __float2bfloat16(vv);
        } else {
          Vsd[(size_t)row * 1024 + col] = vv;  // exact fp32 for residual
          int bb = row >> 11, s = row & 2047;
          Vt[((size_t)bb * 1024 + col) * 2048 + s] = __float2bfloat16(vv);
        }
      }
}

// ---- QK^T per batch: logits = Q[b] * K[b]^T * (1/32), stored bf16 ----
__global__ __launch_bounds__(256) void qk_gemm(const bf16* __restrict__ Qbf,
                                               const bf16* __restrict__ Kbf,
                                               bf16* __restrict__ S) {
  __shared__ bf16 lA[128 * 32];
  __shared__ bf16 lB[128 * 32];
  const int b = blockIdx.z;
  const bf16* At = Qbf + (size_t)b * 2048 * 1024 + (size_t)blockIdx.y * 128 * 1024;
  const bf16* Bt = Kbf + (size_t)b * 2048 * 1024 + (size_t)blockIdx.x * 128 * 1024;
  floatx4 acc[4][4];
  gemm_core(At, Bt, 1024, lA, lB, acc);

  const int tid = threadIdx.x, w = tid >> 6, lane = tid & 63;
  const int subM = (w >> 1) * 64, subN = (w & 1) * 64;
  const int fr = lane & 15, fq = lane >> 4;
  const int rowBase = blockIdx.y * 128 + subM;
  const int colBase = blockIdx.x * 128 + subN;
  bf16* Sb = S + (size_t)b * 2048 * 2048;
#pragma unroll
  for (int i = 0; i < 4; ++i)
#pragma unroll
    for (int j = 0; j < 4; ++j)
#pragma unroll
      for (int r = 0; r < 4; ++r) {
        int row = rowBase + i * 16 + fq * 4 + r;
        int col = colBase + j * 16 + fr;
        Sb[(size_t)row * 2048 + col] = __float2bfloat16(acc[i][j][r] * 0.03125f);
      }
}

// ---- row softmax in place on bf16 logits: 1 block per row of 2048 ----
__global__ __launch_bounds__(256) void softmax_inplace(bf16* __restrict__ S) {
  const size_t row = blockIdx.x;
  bf16* p = S + row * 2048;
  const int t = threadIdx.x;
  float v[8];
  float mx = -3.0e38f;
#pragma unroll
  for (int i = 0; i < 8; ++i) {
    v[i] = __bfloat162float(p[t + i * 256]);
    mx = fmaxf(mx, v[i]);
  }
#pragma unroll
  for (int off = 32; off >= 1; off >>= 1) mx = fmaxf(mx, __shfl_xor(mx, off, 64));
  __shared__ float redm[4];
  __shared__ float reds[4];
  if ((t & 63) == 0) redm[t >> 6] = mx;
  __syncthreads();
  mx = fmaxf(fmaxf(redm[0], redm[1]), fmaxf(redm[2], redm[3]));
  float sum = 0.f;
#pragma unroll
  for (int i = 0; i < 8; ++i) {
    v[i] = __expf(v[i] - mx);
    sum += v[i];
  }
#pragma unroll
  for (int off = 32; off >= 1; off >>= 1) sum += __shfl_xor(sum, off, 64);
  if ((t & 63) == 0) reds[t >> 6] = sum;
  __syncthreads();
  float inv = 1.0f / (reds[0] + reds[1] + reds[2] + reds[3]);
#pragma unroll
  for (int i = 0; i < 8; ++i) p[t + i * 256] = __float2bfloat16(v[i] * inv);
}

// ---- PV per batch: out = P[b][2048,2048] * Vt[b][1024,2048]^T + Vsd ----
__global__ __launch_bounds__(256) void pv_gemm(const bf16* __restrict__ P,
                                               const bf16* __restrict__ Vt,
                                               const float* __restrict__ Vsd,
                                               float* __restrict__ out) {
  __shared__ bf16 lA[128 * 32];
  __shared__ bf16 lB[128 * 32];
  const int b = blockIdx.z;
  const bf16* At = P + (size_t)b * 2048 * 2048 + (size_t)blockIdx.y * 128 * 2048;
  const bf16* Bt = Vt + (size_t)b * 1024 * 2048 + (size_t)blockIdx.x * 128 * 2048;
  floatx4 acc[4][4];
  gemm_core(At, Bt, 2048, lA, lB, acc);

  const int tid = threadIdx.x, w = tid >> 6, lane = tid & 63;
  const int subM = (w >> 1) * 64, subN = (w & 1) * 64;
  const int fr = lane & 15, fq = lane >> 4;
  const int rowBase = blockIdx.y * 128 + subM;
  const int colBase = blockIdx.x * 128 + subN;
#pragma unroll
  for (int i = 0; i < 4; ++i)
#pragma unroll
    for (int j = 0; j < 4; ++j)
#pragma unroll
      for (int r = 0; r < 4; ++r) {
        int row = rowBase + i * 16 + fq * 4 + r;
        int col = colBase + j * 16 + fr;
        size_t oi = ((size_t)b * 2048 + row) * 1024 + col;
        out[oi] = acc[i][j][r] + Vsd[oi];
      }
}

// ---- fp32 -> bf16 cast, 4 elems/thread ----
__global__ void cast_f32_bf16(const float* __restrict__ in, bf16* __restrict__ out, int n4) {
  int i = blockIdx.x * blockDim.x + threadIdx.x;
  if (i < n4) {
    float4 f = ((const float4*)in)[i];
    bf16 tmp[4] = {__float2bfloat16(f.x), __float2bfloat16(f.y),
                   __float2bfloat16(f.z), __float2bfloat16(f.w)};
    ((ushort4*)out)[i] = *(const ushort4*)tmp;
  }
}

extern "C" void kernel_launch(void* const* d_in, const int* in_sizes, int n_in,
                              void* d_out, int out_size, void* d_ws, size_t ws_size,
                              hipStream_t stream) {
  const float* x  = (const float*)d_in[0];
  const float* Wq = (const float*)d_in[1];
  const float* Wk = (const float*)d_in[2];
  const float* Wv = (const float*)d_in[3];
  float* out = (float*)d_out;

  char* ws = (char*)d_ws;
  bf16* Xbf = (bf16*)ws;  ws += (size_t)8192 * 1024 * 2;        // 16 MB
  bf16* Wbf = (bf16*)ws;  ws += (size_t)3 * 1024 * 1024 * 2;    // 6 MB
  bf16* Qbf = (bf16*)ws;  ws += (size_t)8192 * 1024 * 2;        // 16 MB
  bf16* Kbf = (bf16*)ws;  ws += (size_t)8192 * 1024 * 2;        // 16 MB
  bf16* Vt  = (bf16*)ws;  ws += (size_t)4 * 1024 * 2048 * 2;    // 16 MB (V^T per batch)
  float* Vsd = (float*)ws; ws += (size_t)8192 * 1024 * 4;       // 32 MB (fp32 V, residual)
  bf16* S   = (bf16*)ws;  ws += (size_t)4 * 2048 * 2048 * 2;    // 32 MB (logits/probs)

  cast_f32_bf16<<<8192, 256, 0, stream>>>(x, Xbf, 8192 * 1024 / 4);
  cast_f32_bf16<<<1024, 256, 0, stream>>>(Wq, Wbf, 1024 * 1024 / 4);
  cast_f32_bf16<<<1024, 256, 0, stream>>>(Wk, Wbf + 1024 * 1024, 1024 * 1024 / 4);
  cast_f32_bf16<<<1024, 256, 0, stream>>>(Wv, Wbf + 2 * 1024 * 1024, 1024 * 1024 / 4);

  qkv_gemm<<<dim3(8, 64, 3), 256, 0, stream>>>(Xbf, Wbf, Qbf, Kbf, Vt, Vsd);
  qk_gemm<<<dim3(16, 16, 4), 256, 0, stream>>>(Qbf, Kbf, S);
  softmax_inplace<<<8192, 256, 0, stream>>>(S);
  pv_gemm<<<dim3(8, 16, 4), 256, 0, stream>>>(S, Vt, Vsd, out);
}

// Round 2
// 267.134 us; speedup vs baseline: 1.2135x; 1.2135x over previous
//
#include <hip/hip_runtime.h>
#include <hip/hip_bf16.h>

using bf16 = __hip_bfloat16;
typedef __attribute__((ext_vector_type(8))) short short8;   // 8 bf16 = 4 VGPRs
typedef __attribute__((ext_vector_type(4))) float floatx4;  // 4 fp32 acc

// async global->LDS, 16B per lane; dest = wave-uniform base + lane*16, src per-lane
__device__ __forceinline__ void async_ld16(const bf16* g, bf16* l) {
  __builtin_amdgcn_global_load_lds((const __attribute__((address_space(1))) void*)g,
                                   (__attribute__((address_space(3))) void*)l, 16, 0, 0);
}

// 128x128-tile bt-GEMM: C = A[128,K] * B[128,K]^T, bf16 in, fp32 acc. BK=64.
// Block = 256 threads = 4 waves (2x2), each wave a 64x64 subtile (4x4 MFMAs).
// LDS layout XOR-swizzled: chunk position p holds global chunk (row=p>>3,
// j=(p&7)^(row&7)) -> fragment b128 reads are 2-way (free) instead of 8-way.
__device__ __forceinline__ void gemm_core(const bf16* __restrict__ At,
                                          const bf16* __restrict__ Bt,
                                          int K, bf16* lA, bf16* lB,
                                          floatx4 acc[4][4]) {
  const int tid  = threadIdx.x;
  const int w    = tid >> 6;
  const int lane = tid & 63;
  const int subM = (w >> 1) * 64;
  const int subN = (w & 1) * 64;
  const int fr   = lane & 15;
  const int fq   = lane >> 4;

  // staging: tile 128 rows x 64 cols bf16 = 1024 chunks of 16B; 4 calls/thread/tile
  int srow[4], scol[4], sdst[4];
#pragma unroll
  for (int q = 0; q < 4; ++q) {
    int p = q * 256 + w * 64 + lane;
    int r = p >> 3;
    int j = (p & 7) ^ (r & 7);
    srow[q] = r;
    scol[q] = j * 8;
    sdst[q] = (q * 256 + w * 64) * 8;  // wave-uniform element offset
  }
  // fragment LDS element offsets (swizzle applied)
  int offA[2][4], offB[2][4];
#pragma unroll
  for (int kc = 0; kc < 2; ++kc)
#pragma unroll
    for (int i = 0; i < 4; ++i) {
      int rA = subM + i * 16 + fr;
      offA[kc][i] = (rA * 8 + ((kc * 4 + fq) ^ (rA & 7))) * 8;
      int rB = subN + i * 16 + fr;
      offB[kc][i] = (rB * 8 + ((kc * 4 + fq) ^ (rB & 7))) * 8;
    }

  floatx4 zero = {0.f, 0.f, 0.f, 0.f};
#pragma unroll
  for (int i = 0; i < 4; ++i)
#pragma unroll
    for (int j = 0; j < 4; ++j) acc[i][j] = zero;

  for (int k0 = 0; k0 < K; k0 += 64) {
    __syncthreads();
#pragma unroll
    for (int q = 0; q < 4; ++q) {
      async_ld16(At + (size_t)srow[q] * K + k0 + scol[q], lA + sdst[q]);
      async_ld16(Bt + (size_t)srow[q] * K + k0 + scol[q], lB + sdst[q]);
    }
    __syncthreads();  // drains vmcnt; 32 MFMAs per barrier pair below
#pragma unroll
    for (int kc = 0; kc < 2; ++kc) {
      short8 a[4], b[4];
#pragma unroll
      for (int i = 0; i < 4; ++i) a[i] = *(const short8*)(lA + offA[kc][i]);
#pragma unroll
      for (int j = 0; j < 4; ++j) b[j] = *(const short8*)(lB + offB[kc][j]);
#pragma unroll
      for (int i = 0; i < 4; ++i)
#pragma unroll
        for (int j = 0; j < 4; ++j)
          acc[i][j] = __builtin_amdgcn_mfma_f32_16x16x32_bf16(a[i], b[j], acc[i][j], 0, 0, 0);
    }
  }
}

// ---- QKV projection: C = Xbf[8192,1024] * W[z][1024,1024]^T -> bf16 row-major ----
// 1D grid, XCD-swizzled: XCD r owns y-band [8r, 8r+8) -> per-XCD L2 working set ~4MB
__global__ __launch_bounds__(256) void qkv_gemm(const bf16* __restrict__ Xbf,
                                                const bf16* __restrict__ Wbf,
                                                bf16* __restrict__ Qbf,
                                                bf16* __restrict__ Kbf,
                                                bf16* __restrict__ Vbf) {
  __shared__ bf16 lA[128 * 64];
  __shared__ bf16 lB[128 * 64];
  const int id = blockIdx.x;
  const int r = id & 7, g = id >> 3;
  const int ty = r * 8 + (g & 7);
  const int tx = (g >> 3) & 7;
  const int z = g >> 6;

  const bf16* At = Xbf + (size_t)ty * 128 * 1024;
  const bf16* Bt = Wbf + (size_t)z * 1024 * 1024 + (size_t)tx * 128 * 1024;
  floatx4 acc[4][4];
  gemm_core(At, Bt, 1024, lA, lB, acc);

  bf16* dst = (z == 0) ? Qbf : (z == 1) ? Kbf : Vbf;
  const int tid = threadIdx.x, w = tid >> 6, lane = tid & 63;
  const int subM = (w >> 1) * 64, subN = (w & 1) * 64;
  const int fr = lane & 15, fq = lane >> 4;
  const int rowBase = ty * 128 + subM;
  const int colBase = tx * 128 + subN;
#pragma unroll
  for (int i = 0; i < 4; ++i)
#pragma unroll
    for (int j = 0; j < 4; ++j)
#pragma unroll
      for (int rr = 0; rr < 4; ++rr) {
        int row = rowBase + i * 16 + fq * 4 + rr;
        int col = colBase + j * 16 + fr;
        dst[(size_t)row * 1024 + col] = __float2bfloat16(acc[i][j][rr]);
      }
}

// ---- V transpose: Vbf[4][2048][1024] -> Vt[4][1024][2048] (bf16) ----
__global__ __launch_bounds__(256) void transpose_v(const bf16* __restrict__ Vbf,
                                                   bf16* __restrict__ Vt) {
  __shared__ short tile[64][72];  // +8 pad keeps 16B alignment, breaks bank stride
  const int b = blockIdx.z;
  const int s0 = blockIdx.x * 64;
  const int v0 = blockIdx.y * 64;
  const int t = threadIdx.x;
#pragma unroll
  for (int i = 0; i < 2; ++i) {
    int c = t + i * 256;           // 512 chunks of 8 elems
    int row = c >> 3, cj = c & 7;
    *(short8*)&tile[row][cj * 8] =
        *(const short8*)&Vbf[((size_t)(b * 2048 + s0 + row)) * 1024 + v0 + cj * 8];
  }
  __syncthreads();
  const int vrow = t >> 2, sq = t & 3;
#pragma unroll
  for (int hc = 0; hc < 2; ++hc) {
    short8 vv;
#pragma unroll
    for (int e = 0; e < 8; ++e) vv[e] = tile[sq * 16 + hc * 8 + e][vrow];
    *(short8*)&Vt[((size_t)(b * 1024 + v0 + vrow)) * 2048 + s0 + sq * 16 + hc * 8] = vv;
  }
}

// ---- QK^T per batch: logits = Q[b] * K[b]^T * (1/32), stored bf16 ----
__global__ __launch_bounds__(256) void qk_gemm(const bf16* __restrict__ Qbf,
                                               const bf16* __restrict__ Kbf,
                                               bf16* __restrict__ S) {
  __shared__ bf16 lA[128 * 64];
  __shared__ bf16 lB[128 * 64];
  const int id = blockIdx.x;
  const int r = id & 7, g = id >> 3;
  const int b = g >> 5;
  const int rem = g & 31;
  const int ty = r * 2 + (rem & 1);
  const int tx = rem >> 1;

  const bf16* At = Qbf + (size_t)b * 2048 * 1024 + (size_t)ty * 128 * 1024;
  const bf16* Bt = Kbf + (size_t)b * 2048 * 1024 + (size_t)tx * 128 * 1024;
  floatx4 acc[4][4];
  gemm_core(At, Bt, 1024, lA, lB, acc);

  const int tid = threadIdx.x, w = tid >> 6, lane = tid & 63;
  const int subM = (w >> 1) * 64, subN = (w & 1) * 64;
  const int fr = lane & 15, fq = lane >> 4;
  const int rowBase = ty * 128 + subM;
  const int colBase = tx * 128 + subN;
  bf16* Sb = S + (size_t)b * 2048 * 2048;
#pragma unroll
  for (int i = 0; i < 4; ++i)
#pragma unroll
    for (int j = 0; j < 4; ++j)
#pragma unroll
      for (int rr = 0; rr < 4; ++rr) {
        int row = rowBase + i * 16 + fq * 4 + rr;
        int col = colBase + j * 16 + fr;
        Sb[(size_t)row * 2048 + col] = __float2bfloat16(acc[i][j][rr] * 0.03125f);
      }
}

// ---- row softmax in place on bf16 logits: 1 block per row of 2048 ----
__global__ __launch_bounds__(256) void softmax_inplace(bf16* __restrict__ S) {
  const size_t row = blockIdx.x;
  bf16* p = S + row * 2048;
  const int t = threadIdx.x;
  float v[8];
  float mx = -3.0e38f;
#pragma unroll
  for (int i = 0; i < 8; ++i) {
    v[i] = __bfloat162float(p[t + i * 256]);
    mx = fmaxf(mx, v[i]);
  }
#pragma unroll
  for (int off = 32; off >= 1; off >>= 1) mx = fmaxf(mx, __shfl_xor(mx, off, 64));
  __shared__ float redm[4];
  __shared__ float reds[4];
  if ((t & 63) == 0) redm[t >> 6] = mx;
  __syncthreads();
  mx = fmaxf(fmaxf(redm[0], redm[1]), fmaxf(redm[2], redm[3]));
  float sum = 0.f;
#pragma unroll
  for (int i = 0; i < 8; ++i) {
    v[i] = __expf(v[i] - mx);
    sum += v[i];
  }
#pragma unroll
  for (int off = 32; off >= 1; off >>= 1) sum += __shfl_xor(sum, off, 64);
  if ((t & 63) == 0) reds[t >> 6] = sum;
  __syncthreads();
  float inv = 1.0f / (reds[0] + reds[1] + reds[2] + reds[3]);
#pragma unroll
  for (int i = 0; i < 8; ++i) p[t + i * 256] = __float2bfloat16(v[i] * inv);
}

// ---- PV per batch: out = P[b][2048,2048] * Vt[b][1024,2048]^T + Vbf (residual) ----
__global__ __launch_bounds__(256) void pv_gemm(const bf16* __restrict__ P,
                                               const bf16* __restrict__ Vt,
                                               const bf16* __restrict__ Vbf,
                                               float* __restrict__ out) {
  __shared__ bf16 lA[128 * 64];
  __shared__ bf16 lB[128 * 64];
  const int id = blockIdx.x;
  const int r = id & 7, g = id >> 3;
  const int b = g >> 4;
  const int rem = g & 15;
  const int ty = r * 2 + (rem & 1);
  const int tx = rem >> 1;

  const bf16* At = P + (size_t)b * 2048 * 2048 + (size_t)ty * 128 * 2048;
  const bf16* Bt = Vt + (size_t)b * 1024 * 2048 + (size_t)tx * 128 * 2048;
  floatx4 acc[4][4];
  gemm_core(At, Bt, 2048, lA, lB, acc);

  const int tid = threadIdx.x, w = tid >> 6, lane = tid & 63;
  const int subM = (w >> 1) * 64, subN = (w & 1) * 64;
  const int fr = lane & 15, fq = lane >> 4;
  const int rowBase = ty * 128 + subM;
  const int colBase = tx * 128 + subN;
#pragma unroll
  for (int i = 0; i < 4; ++i)
#pragma unroll
    for (int j = 0; j < 4; ++j)
#pragma unroll
      for (int rr = 0; rr < 4; ++rr) {
        int row = rowBase + i * 16 + fq * 4 + rr;
        int col = colBase + j * 16 + fr;
        size_t oi = ((size_t)b * 2048 + row) * 1024 + col;
        out[oi] = acc[i][j][rr] + __bfloat162float(Vbf[oi]);
      }
}

// ---- fp32 -> bf16 cast, 4 elems/thread ----
__global__ void cast_f32_bf16(const float* __restrict__ in, bf16* __restrict__ out, int n4) {
  int i = blockIdx.x * blockDim.x + threadIdx.x;
  if (i < n4) {
    float4 f = ((const float4*)in)[i];
    bf16 tmp[4] = {__float2bfloat16(f.x), __float2bfloat16(f.y),
                   __float2bfloat16(f.z), __float2bfloat16(f.w)};
    ((ushort4*)out)[i] = *(const ushort4*)tmp;
  }
}

extern "C" void kernel_launch(void* const* d_in, const int* in_sizes, int n_in,
                              void* d_out, int out_size, void* d_ws, size_t ws_size,
                              hipStream_t stream) {
  const float* x  = (const float*)d_in[0];
  const float* Wq = (const float*)d_in[1];
  const float* Wk = (const float*)d_in[2];
  const float* Wv = (const float*)d_in[3];
  float* out = (float*)d_out;

  char* ws = (char*)d_ws;
  bf16* Xbf = (bf16*)ws;  ws += (size_t)8192 * 1024 * 2;        // 16 MB
  bf16* Wbf = (bf16*)ws;  ws += (size_t)3 * 1024 * 1024 * 2;    // 6 MB
  bf16* Qbf = (bf16*)ws;  ws += (size_t)8192 * 1024 * 2;        // 16 MB
  bf16* Kbf = (bf16*)ws;  ws += (size_t)8192 * 1024 * 2;        // 16 MB
  bf16* Vbf = (bf16*)ws;  ws += (size_t)8192 * 1024 * 2;        // 16 MB (row-major V, residual)
  bf16* Vt  = (bf16*)ws;  ws += (size_t)4 * 1024 * 2048 * 2;    // 16 MB (V^T per batch)
  bf16* S   = (bf16*)ws;  ws += (size_t)4 * 2048 * 2048 * 2;    // 32 MB (logits/probs)

  cast_f32_bf16<<<8192, 256, 0, stream>>>(x, Xbf, 8192 * 1024 / 4);
  cast_f32_bf16<<<1024, 256, 0, stream>>>(Wq, Wbf, 1024 * 1024 / 4);
  cast_f32_bf16<<<1024, 256, 0, stream>>>(Wk, Wbf + 1024 * 1024, 1024 * 1024 / 4);
  cast_f32_bf16<<<1024, 256, 0, stream>>>(Wv, Wbf + 2 * 1024 * 1024, 1024 * 1024 / 4);

  qkv_gemm<<<1536, 256, 0, stream>>>(Xbf, Wbf, Qbf, Kbf, Vbf);
  transpose_v<<<dim3(32, 16, 4), 256, 0, stream>>>(Vbf, Vt);
  qk_gemm<<<1024, 256, 0, stream>>>(Qbf, Kbf, S);
  softmax_inplace<<<8192, 256, 0, stream>>>(S);
  pv_gemm<<<512, 256, 0, stream>>>(S, Vt, Vbf, out);
}

// Round 3
// 258.260 us; speedup vs baseline: 1.2552x; 1.0344x over previous
//
#include <hip/hip_runtime.h>
#include <hip/hip_bf16.h>

using bf16 = __hip_bfloat16;
typedef __attribute__((ext_vector_type(8))) short short8;   // 8 bf16 = 4 VGPRs
typedef __attribute__((ext_vector_type(4))) float floatx4;  // 4 fp32 acc

// async global->LDS, 16B per lane; dest = wave-uniform base + lane*16, src per-lane
__device__ __forceinline__ void async_ld16(const bf16* g, bf16* l) {
  __builtin_amdgcn_global_load_lds((const __attribute__((address_space(1))) void*)g,
                                   (__attribute__((address_space(3))) void*)l, 16, 0, 0);
}

// 128x128-tile bt-GEMM: C = A[128,K] * B[128,K]^T, bf16 in, fp32 acc. BK=64.
// Block = 256 threads = 4 waves (2x2), each wave a 64x64 subtile (4x4 MFMAs).
// LDS XOR-swizzled (R2: bank conflicts 6.3M -> 0).
__device__ __forceinline__ void gemm_core(const bf16* __restrict__ At,
                                          const bf16* __restrict__ Bt,
                                          int K, bf16* lA, bf16* lB,
                                          floatx4 acc[4][4]) {
  const int tid  = threadIdx.x;
  const int w    = tid >> 6;
  const int lane = tid & 63;
  const int subM = (w >> 1) * 64;
  const int subN = (w & 1) * 64;
  const int fr   = lane & 15;
  const int fq   = lane >> 4;

  int srow[4], scol[4], sdst[4];
#pragma unroll
  for (int q = 0; q < 4; ++q) {
    int p = q * 256 + w * 64 + lane;
    int r = p >> 3;
    int j = (p & 7) ^ (r & 7);
    srow[q] = r;
    scol[q] = j * 8;
    sdst[q] = (q * 256 + w * 64) * 8;
  }
  int offA[2][4], offB[2][4];
#pragma unroll
  for (int kc = 0; kc < 2; ++kc)
#pragma unroll
    for (int i = 0; i < 4; ++i) {
      int rA = subM + i * 16 + fr;
      offA[kc][i] = (rA * 8 + ((kc * 4 + fq) ^ (rA & 7))) * 8;
      int rB = subN + i * 16 + fr;
      offB[kc][i] = (rB * 8 + ((kc * 4 + fq) ^ (rB & 7))) * 8;
    }

  floatx4 zero = {0.f, 0.f, 0.f, 0.f};
#pragma unroll
  for (int i = 0; i < 4; ++i)
#pragma unroll
    for (int j = 0; j < 4; ++j) acc[i][j] = zero;

  for (int k0 = 0; k0 < K; k0 += 64) {
    __syncthreads();
#pragma unroll
    for (int q = 0; q < 4; ++q) {
      async_ld16(At + (size_t)srow[q] * K + k0 + scol[q], lA + sdst[q]);
      async_ld16(Bt + (size_t)srow[q] * K + k0 + scol[q], lB + sdst[q]);
    }
    __syncthreads();
#pragma unroll
    for (int kc = 0; kc < 2; ++kc) {
      short8 a[4], b[4];
#pragma unroll
      for (int i = 0; i < 4; ++i) a[i] = *(const short8*)(lA + offA[kc][i]);
#pragma unroll
      for (int j = 0; j < 4; ++j) b[j] = *(const short8*)(lB + offB[kc][j]);
#pragma unroll
      for (int i = 0; i < 4; ++i)
#pragma unroll
        for (int j = 0; j < 4; ++j)
          acc[i][j] = __builtin_amdgcn_mfma_f32_16x16x32_bf16(a[i], b[j], acc[i][j], 0, 0, 0);
    }
  }
}

// ---- QKV projection. Q pre-scaled by 2^-5 (exact). ----
__global__ __launch_bounds__(256) void qkv_gemm(const bf16* __restrict__ Xbf,
                                                const bf16* __restrict__ Wbf,
                                                bf16* __restrict__ Qbf,
                                                bf16* __restrict__ Kbf,
                                                bf16* __restrict__ Vbf) {
  __shared__ bf16 lA[128 * 64];
  __shared__ bf16 lB[128 * 64];
  const int id = blockIdx.x;
  const int r = id & 7, g = id >> 3;
  const int ty = r * 8 + (g & 7);
  const int tx = (g >> 3) & 7;
  const int z = g >> 6;

  const bf16* At = Xbf + (size_t)ty * 128 * 1024;
  const bf16* Bt = Wbf + (size_t)z * 1024 * 1024 + (size_t)tx * 128 * 1024;
  floatx4 acc[4][4];
  gemm_core(At, Bt, 1024, lA, lB, acc);

  bf16* dst = (z == 0) ? Qbf : (z == 1) ? Kbf : Vbf;
  const float sc = (z == 0) ? 0.03125f : 1.0f;  // fold norm_fact into Q (pow2, exact)
  const int tid = threadIdx.x, w = tid >> 6, lane = tid & 63;
  const int subM = (w >> 1) * 64, subN = (w & 1) * 64;
  const int fr = lane & 15, fq = lane >> 4;
  const int rowBase = ty * 128 + subM;
  const int colBase = tx * 128 + subN;
#pragma unroll
  for (int i = 0; i < 4; ++i)
#pragma unroll
    for (int j = 0; j < 4; ++j)
#pragma unroll
      for (int rr = 0; rr < 4; ++rr) {
        int row = rowBase + i * 16 + fq * 4 + rr;
        int col = colBase + j * 16 + fr;
        dst[(size_t)row * 1024 + col] = __float2bfloat16(acc[i][j][rr] * sc);
      }
}

// ---- V transpose: Vbf[4][2048][1024] -> Vt[4][1024][2048] ----
__global__ __launch_bounds__(256) void transpose_v(const bf16* __restrict__ Vbf,
                                                   bf16* __restrict__ Vt) {
  __shared__ short tile[64][72];
  const int b = blockIdx.z;
  const int s0 = blockIdx.x * 64;
  const int v0 = blockIdx.y * 64;
  const int t = threadIdx.x;
#pragma unroll
  for (int i = 0; i < 2; ++i) {
    int c = t + i * 256;
    int row = c >> 3, cj = c & 7;
    *(short8*)&tile[row][cj * 8] =
        *(const short8*)&Vbf[((size_t)(b * 2048 + s0 + row)) * 1024 + v0 + cj * 8];
  }
  __syncthreads();
  const int vrow = t >> 2, sq = t & 3;
#pragma unroll
  for (int hc = 0; hc < 2; ++hc) {
    short8 vv;
#pragma unroll
    for (int e = 0; e < 8; ++e) vv[e] = tile[sq * 16 + hc * 8 + e][vrow];
    *(short8*)&Vt[((size_t)(b * 1024 + v0 + vrow)) * 2048 + s0 + sq * 16 + hc * 8] = vv;
  }
}

// ---- QK^T + exp fused: E = exp(Q*K^T) bf16; row-sums l via atomics ----
// No max-subtraction: logits bounded |s| <~ 11 (Cauchy-Schwarz), exp safe in fp32.
__global__ __launch_bounds__(256) void qk_exp_gemm(const bf16* __restrict__ Qbf,
                                                   const bf16* __restrict__ Kbf,
                                                   bf16* __restrict__ S,
                                                   float* __restrict__ l) {
  __shared__ bf16 lA[128 * 64];
  __shared__ bf16 lB[128 * 64];
  const int id = blockIdx.x;
  const int r = id & 7, g = id >> 3;
  const int b = g >> 5;
  const int rem = g & 31;
  const int ty = r * 2 + (rem & 1);
  const int tx = rem >> 1;

  const bf16* At = Qbf + (size_t)b * 2048 * 1024 + (size_t)ty * 128 * 1024;
  const bf16* Bt = Kbf + (size_t)b * 2048 * 1024 + (size_t)tx * 128 * 1024;
  floatx4 acc[4][4];
  gemm_core(At, Bt, 1024, lA, lB, acc);

  const int tid = threadIdx.x, w = tid >> 6, lane = tid & 63;
  const int subM = (w >> 1) * 64, subN = (w & 1) * 64;
  const int fr = lane & 15, fq = lane >> 4;
  const int rowBase = ty * 128 + subM;
  const int colBase = tx * 128 + subN;
  bf16* Sb = S + (size_t)b * 2048 * 2048;
  float* lb = l + (size_t)b * 2048;
#pragma unroll
  for (int i = 0; i < 4; ++i)
#pragma unroll
    for (int rr = 0; rr < 4; ++rr) {
      int row = rowBase + i * 16 + fq * 4 + rr;
      float psum = 0.f;
#pragma unroll
      for (int j = 0; j < 4; ++j) {
        int col = colBase + j * 16 + fr;
        float e = __expf(acc[i][j][rr]);
        bf16 eb = __float2bfloat16(e);
        Sb[(size_t)row * 2048 + col] = eb;
        psum += __bfloat162float(eb);  // sum what pv will actually consume
      }
      // reduce across fr (lane bits 0-3; stays within quad)
      psum += __shfl_xor(psum, 1, 64);
      psum += __shfl_xor(psum, 2, 64);
      psum += __shfl_xor(psum, 4, 64);
      psum += __shfl_xor(psum, 8, 64);
      if (fr == 0) atomicAdd(&lb[row], psum);
    }
}

// ---- PV + normalize + residual: out = (E * Vt^T)/l + V ----
__global__ __launch_bounds__(256) void pv_gemm(const bf16* __restrict__ P,
                                               const bf16* __restrict__ Vt,
                                               const bf16* __restrict__ Vbf,
                                               const float* __restrict__ l,
                                               float* __restrict__ out) {
  __shared__ bf16 lA[128 * 64];
  __shared__ bf16 lB[128 * 64];
  const int id = blockIdx.x;
  const int r = id & 7, g = id >> 3;
  const int b = g >> 4;
  const int rem = g & 15;
  const int ty = r * 2 + (rem & 1);
  const int tx = rem >> 1;

  const bf16* At = P + (size_t)b * 2048 * 2048 + (size_t)ty * 128 * 2048;
  const bf16* Bt = Vt + (size_t)b * 1024 * 2048 + (size_t)tx * 128 * 2048;
  floatx4 acc[4][4];
  gemm_core(At, Bt, 2048, lA, lB, acc);

  const int tid = threadIdx.x, w = tid >> 6, lane = tid & 63;
  const int subM = (w >> 1) * 64, subN = (w & 1) * 64;
  const int fr = lane & 15, fq = lane >> 4;
  const int rowBase = ty * 128 + subM;
  const int colBase = tx * 128 + subN;
  const float* lb = l + (size_t)b * 2048;
#pragma unroll
  for (int i = 0; i < 4; ++i)
#pragma unroll
    for (int rr = 0; rr < 4; ++rr) {
      int row = rowBase + i * 16 + fq * 4 + rr;
      float inv = 1.0f / lb[row];
#pragma unroll
      for (int j = 0; j < 4; ++j) {
        int col = colBase + j * 16 + fr;
        size_t oi = ((size_t)b * 2048 + row) * 1024 + col;
        out[oi] = acc[i][j][rr] * inv + __bfloat162float(Vbf[oi]);
      }
    }
}

// ---- one cast kernel for x + Wq + Wk + Wv (1024 elems per block) ----
__global__ void cast_all(const float* __restrict__ x, const float* __restrict__ wq,
                         const float* __restrict__ wk, const float* __restrict__ wv,
                         bf16* __restrict__ Xbf, bf16* __restrict__ Wbf) {
  const int blk = blockIdx.x;
  const float* src;
  bf16* dst;
  int base;
  if (blk < 8192)       { src = x;  dst = Xbf;                 base = blk; }
  else if (blk < 9216)  { src = wq; dst = Wbf;                 base = blk - 8192; }
  else if (blk < 10240) { src = wk; dst = Wbf + 1024 * 1024;   base = blk - 9216; }
  else                  { src = wv; dst = Wbf + 2 * 1024 * 1024; base = blk - 10240; }
  int i = base * 256 + threadIdx.x;
  float4 f = ((const float4*)src)[i];
  bf16 tmp[4] = {__float2bfloat16(f.x), __float2bfloat16(f.y),
                 __float2bfloat16(f.z), __float2bfloat16(f.w)};
  ((ushort4*)dst)[i] = *(const ushort4*)tmp;
}

extern "C" void kernel_launch(void* const* d_in, const int* in_sizes, int n_in,
                              void* d_out, int out_size, void* d_ws, size_t ws_size,
                              hipStream_t stream) {
  const float* x  = (const float*)d_in[0];
  const float* Wq = (const float*)d_in[1];
  const float* Wk = (const float*)d_in[2];
  const float* Wv = (const float*)d_in[3];
  float* out = (float*)d_out;

  char* ws = (char*)d_ws;
  bf16* Xbf = (bf16*)ws;  ws += (size_t)8192 * 1024 * 2;        // 16 MB
  bf16* Wbf = (bf16*)ws;  ws += (size_t)3 * 1024 * 1024 * 2;    // 6 MB
  bf16* Qbf = (bf16*)ws;  ws += (size_t)8192 * 1024 * 2;        // 16 MB
  bf16* Kbf = (bf16*)ws;  ws += (size_t)8192 * 1024 * 2;        // 16 MB
  bf16* Vbf = (bf16*)ws;  ws += (size_t)8192 * 1024 * 2;        // 16 MB
  bf16* Vt  = (bf16*)ws;  ws += (size_t)4 * 1024 * 2048 * 2;    // 16 MB
  bf16* S   = (bf16*)ws;  ws += (size_t)4 * 2048 * 2048 * 2;    // 32 MB (unnorm exp)
  float* l  = (float*)ws; ws += (size_t)8192 * 4;               // row sums

  hipMemsetAsync(l, 0, 8192 * sizeof(float), stream);
  cast_all<<<11264, 256, 0, stream>>>(x, Wq, Wk, Wv, Xbf, Wbf);
  qkv_gemm<<<1536, 256, 0, stream>>>(Xbf, Wbf, Qbf, Kbf, Vbf);
  transpose_v<<<dim3(32, 16, 4), 256, 0, stream>>>(Vbf, Vt);
  qk_exp_gemm<<<1024, 256, 0, stream>>>(Qbf, Kbf, S, l);
  pv_gemm<<<512, 256, 0, stream>>>(S, Vt, Vbf, l, out);
}

// Round 4
// 225.293 us; speedup vs baseline: 1.4389x; 1.1463x over previous
//
#include <hip/hip_runtime.h>
#include <hip/hip_bf16.h>
#include <hip/hip_fp8.h>

using bf16 = __hip_bfloat16;
typedef __attribute__((ext_vector_type(8))) short short8;   // 8 bf16 = 4 VGPRs
typedef __attribute__((ext_vector_type(4))) float floatx4;  // 4 fp32 acc
typedef __attribute__((ext_vector_type(8))) int int8v;      // 32 fp8 = 8 VGPRs

__device__ __forceinline__ void async_ld16(const void* g, void* l) {
  __builtin_amdgcn_global_load_lds((const __attribute__((address_space(1))) void*)g,
                                   (__attribute__((address_space(3))) void*)l, 16, 0, 0);
}

__device__ __forceinline__ unsigned char to_fp8(float f) {
  __hip_fp8_e4m3 q(f);
  return q.__x;
}
__device__ __forceinline__ float from_fp8(unsigned char b) {
  __hip_fp8_e4m3 q;
  q.__x = b;
  return (float)q;
}

// ---------------- bf16 128x128 tile core (BK=64), XOR-swizzled LDS ----------------
__device__ __forceinline__ void gemm_core(const bf16* __restrict__ At,
                                          const bf16* __restrict__ Bt,
                                          int K, bf16* lA, bf16* lB,
                                          floatx4 acc[4][4]) {
  const int tid  = threadIdx.x;
  const int w    = tid >> 6;
  const int lane = tid & 63;
  const int subM = (w >> 1) * 64;
  const int subN = (w & 1) * 64;
  const int fr   = lane & 15;
  const int fq   = lane >> 4;

  int srow[4], scol[4], sdst[4];
#pragma unroll
  for (int q = 0; q < 4; ++q) {
    int p = q * 256 + w * 64 + lane;
    int r = p >> 3;
    int j = (p & 7) ^ (r & 7);
    srow[q] = r;
    scol[q] = j * 8;
    sdst[q] = (q * 256 + w * 64) * 8;
  }
  int offA[2][4], offB[2][4];
#pragma unroll
  for (int kc = 0; kc < 2; ++kc)
#pragma unroll
    for (int i = 0; i < 4; ++i) {
      int rA = subM + i * 16 + fr;
      offA[kc][i] = (rA * 8 + ((kc * 4 + fq) ^ (rA & 7))) * 8;
      int rB = subN + i * 16 + fr;
      offB[kc][i] = (rB * 8 + ((kc * 4 + fq) ^ (rB & 7))) * 8;
    }

  floatx4 zero = {0.f, 0.f, 0.f, 0.f};
#pragma unroll
  for (int i = 0; i < 4; ++i)
#pragma unroll
    for (int j = 0; j < 4; ++j) acc[i][j] = zero;

  for (int k0 = 0; k0 < K; k0 += 64) {
    __syncthreads();
#pragma unroll
    for (int q = 0; q < 4; ++q) {
      async_ld16(At + (size_t)srow[q] * K + k0 + scol[q], lA + sdst[q]);
      async_ld16(Bt + (size_t)srow[q] * K + k0 + scol[q], lB + sdst[q]);
    }
    __syncthreads();
#pragma unroll
    for (int kc = 0; kc < 2; ++kc) {
      short8 a[4], b[4];
#pragma unroll
      for (int i = 0; i < 4; ++i) a[i] = *(const short8*)(lA + offA[kc][i]);
#pragma unroll
      for (int j = 0; j < 4; ++j) b[j] = *(const short8*)(lB + offB[kc][j]);
#pragma unroll
      for (int i = 0; i < 4; ++i)
#pragma unroll
        for (int j = 0; j < 4; ++j)
          acc[i][j] = __builtin_amdgcn_mfma_f32_16x16x32_bf16(a[i], b[j], acc[i][j], 0, 0, 0);
    }
  }
}

// ---------------- fp8 (MX-scaled, scales=1.0) 128x128 tile core (BK=128) ----------
// Same LDS byte-geometry as bf16 core: 128 rows x 128 bytes, 8 chunks of 16B/row,
// chunk j stored at position j^(row&7) -> 2-way (free) b128 fragment reads.
// MFMA: 16x16x128 f8f6f4, fp8/fp8, e8m0 scales = 127 (2^0) -> plain fp8 GEMM at 2x rate.
__device__ __forceinline__ void gemm_core_f8(const unsigned char* __restrict__ At,
                                             const unsigned char* __restrict__ Bt,
                                             int K, unsigned char* lA, unsigned char* lB,
                                             floatx4 acc[4][4]) {
  const int tid  = threadIdx.x;
  const int w    = tid >> 6;
  const int lane = tid & 63;
  const int subM = (w >> 1) * 64;
  const int subN = (w & 1) * 64;
  const int fr   = lane & 15;
  const int fq   = lane >> 4;

  int srow[4], scol[4], sdst[4];
#pragma unroll
  for (int q = 0; q < 4; ++q) {
    int p = q * 256 + w * 64 + lane;
    int r = p >> 3;
    int j = (p & 7) ^ (r & 7);
    srow[q] = r;
    scol[q] = j * 16;       // byte col
    sdst[q] = (q * 256 + w * 64) * 16;  // byte dst (wave-uniform base + lane*16)
  }
  // fragment byte offsets: lane covers k = fq*32 + [0..31] = chunks fq*2, fq*2+1
  int offA[2][4], offB[2][4];
#pragma unroll
  for (int h = 0; h < 2; ++h)
#pragma unroll
    for (int i = 0; i < 4; ++i) {
      int rA = subM + i * 16 + fr;
      offA[h][i] = rA * 128 + (((fq * 2 + h) ^ (rA & 7)) * 16);
      int rB = subN + i * 16 + fr;
      offB[h][i] = rB * 128 + (((fq * 2 + h) ^ (rB & 7)) * 16);
    }

  floatx4 zero = {0.f, 0.f, 0.f, 0.f};
#pragma unroll
  for (int i = 0; i < 4; ++i)
#pragma unroll
    for (int j = 0; j < 4; ++j) acc[i][j] = zero;

  for (int k0 = 0; k0 < K; k0 += 128) {
    __syncthreads();
#pragma unroll
    for (int q = 0; q < 4; ++q) {
      async_ld16(At + (size_t)srow[q] * K + k0 + scol[q], lA + sdst[q]);
      async_ld16(Bt + (size_t)srow[q] * K + k0 + scol[q], lB + sdst[q]);
    }
    __syncthreads();
    int8v a[4], b[4];
#pragma unroll
    for (int i = 0; i < 4; ++i) {
      int4 lo = *(const int4*)(lA + offA[0][i]);
      int4 hi = *(const int4*)(lA + offA[1][i]);
      int8v v;
      v[0] = lo.x; v[1] = lo.y; v[2] = lo.z; v[3] = lo.w;
      v[4] = hi.x; v[5] = hi.y; v[6] = hi.z; v[7] = hi.w;
      a[i] = v;
    }
#pragma unroll
    for (int j = 0; j < 4; ++j) {
      int4 lo = *(const int4*)(lB + offB[0][j]);
      int4 hi = *(const int4*)(lB + offB[1][j]);
      int8v v;
      v[0] = lo.x; v[1] = lo.y; v[2] = lo.z; v[3] = lo.w;
      v[4] = hi.x; v[5] = hi.y; v[6] = hi.z; v[7] = hi.w;
      b[j] = v;
    }
#pragma unroll
    for (int i = 0; i < 4; ++i)
#pragma unroll
      for (int j = 0; j < 4; ++j)
        acc[i][j] = __builtin_amdgcn_mfma_scale_f32_16x16x128_f8f6f4(
            a[i], b[j], acc[i][j], 0 /*fp8 A*/, 0 /*fp8 B*/,
            0, 0x7F7F7F7F, 0, 0x7F7F7F7F);  // e8m0 127 = scale 1.0 everywhere
  }
}

// ---- QKV projection (bf16 core): Q,K out as fp8 e4m3 (unscaled); V out as bf16 ----
__global__ __launch_bounds__(256) void qkv_gemm(const bf16* __restrict__ Xbf,
                                                const bf16* __restrict__ Wbf,
                                                unsigned char* __restrict__ Qf8,
                                                unsigned char* __restrict__ Kf8,
                                                bf16* __restrict__ Vbf) {
  __shared__ bf16 lA[128 * 64];
  __shared__ bf16 lB[128 * 64];
  const int id = blockIdx.x;
  const int r = id & 7, g = id >> 3;
  const int ty = r * 8 + (g & 7);
  const int tx = (g >> 3) & 7;
  const int z = g >> 6;

  const bf16* At = Xbf + (size_t)ty * 128 * 1024;
  const bf16* Bt = Wbf + (size_t)z * 1024 * 1024 + (size_t)tx * 128 * 1024;
  floatx4 acc[4][4];
  gemm_core(At, Bt, 1024, lA, lB, acc);

  const int tid = threadIdx.x, w = tid >> 6, lane = tid & 63;
  const int subM = (w >> 1) * 64, subN = (w & 1) * 64;
  const int fr = lane & 15, fq = lane >> 4;
  const int rowBase = ty * 128 + subM;
  const int colBase = tx * 128 + subN;
#pragma unroll
  for (int i = 0; i < 4; ++i)
#pragma unroll
    for (int j = 0; j < 4; ++j)
#pragma unroll
      for (int rr = 0; rr < 4; ++rr) {
        int row = rowBase + i * 16 + fq * 4 + rr;
        int col = colBase + j * 16 + fr;
        float vv = acc[i][j][rr];
        if (z == 0)      Qf8[(size_t)row * 1024 + col] = to_fp8(vv);
        else if (z == 1) Kf8[(size_t)row * 1024 + col] = to_fp8(vv);
        else             Vbf[(size_t)row * 1024 + col] = __float2bfloat16(vv);
      }
}

// ---- V transpose: Vbf[4][2048][1024] bf16 -> Vt8[4][1024][2048] fp8 ----
__global__ __launch_bounds__(256) void transpose_v(const bf16* __restrict__ Vbf,
                                                   unsigned char* __restrict__ Vt8) {
  __shared__ short tile[64][72];
  const int b = blockIdx.z;
  const int s0 = blockIdx.x * 64;
  const int v0 = blockIdx.y * 64;
  const int t = threadIdx.x;
#pragma unroll
  for (int i = 0; i < 2; ++i) {
    int c = t + i * 256;
    int row = c >> 3, cj = c & 7;
    *(short8*)&tile[row][cj * 8] =
        *(const short8*)&Vbf[((size_t)(b * 2048 + s0 + row)) * 1024 + v0 + cj * 8];
  }
  __syncthreads();
  const int vrow = t >> 2, sq = t & 3;
#pragma unroll
  for (int hc = 0; hc < 2; ++hc) {
    unsigned char vv[8];
#pragma unroll
    for (int e = 0; e < 8; ++e) {
      short s = tile[sq * 16 + hc * 8 + e][vrow];
      bf16 h = *(bf16*)&s;
      vv[e] = to_fp8(__bfloat162float(h));
    }
    *(uint2*)&Vt8[((size_t)(b * 1024 + v0 + vrow)) * 2048 + s0 + sq * 16 + hc * 8] =
        *(const uint2*)vv;
  }
}

// ---- QK^T (fp8 MX core) + exp fused: E = exp(s/32) fp8; row-sums l ----
__global__ __launch_bounds__(256) void qk_exp_gemm(const unsigned char* __restrict__ Qf8,
                                                   const unsigned char* __restrict__ Kf8,
                                                   unsigned char* __restrict__ S8,
                                                   float* __restrict__ l) {
  __shared__ unsigned char lA[128 * 128];
  __shared__ unsigned char lB[128 * 128];
  const int id = blockIdx.x;
  const int r = id & 7, g = id >> 3;
  const int b = g >> 5;
  const int rem = g & 31;
  const int ty = r * 2 + (rem & 1);
  const int tx = rem >> 1;

  const unsigned char* At = Qf8 + (size_t)b * 2048 * 1024 + (size_t)ty * 128 * 1024;
  const unsigned char* Bt = Kf8 + (size_t)b * 2048 * 1024 + (size_t)tx * 128 * 1024;
  floatx4 acc[4][4];
  gemm_core_f8(At, Bt, 1024, lA, lB, acc);

  const int tid = threadIdx.x, w = tid >> 6, lane = tid & 63;
  const int subM = (w >> 1) * 64, subN = (w & 1) * 64;
  const int fr = lane & 15, fq = lane >> 4;
  const int rowBase = ty * 128 + subM;
  const int colBase = tx * 128 + subN;
  unsigned char* Sb = S8 + (size_t)b * 2048 * 2048;
  float* lb = l + (size_t)b * 2048;
#pragma unroll
  for (int i = 0; i < 4; ++i)
#pragma unroll
    for (int rr = 0; rr < 4; ++rr) {
      int row = rowBase + i * 16 + fq * 4 + rr;
      float psum = 0.f;
#pragma unroll
      for (int j = 0; j < 4; ++j) {
        int col = colBase + j * 16 + fr;
        float e = __expf(acc[i][j][rr] * 0.03125f);  // norm_fact applied here
        unsigned char eb = to_fp8(e);
        Sb[(size_t)row * 2048 + col] = eb;
        psum += from_fp8(eb);  // sum exactly what pv consumes
      }
      psum += __shfl_xor(psum, 1, 64);
      psum += __shfl_xor(psum, 2, 64);
      psum += __shfl_xor(psum, 4, 64);
      psum += __shfl_xor(psum, 8, 64);
      if (fr == 0) atomicAdd(&lb[row], psum);
    }
}

// ---- PV (fp8 MX core) + normalize + residual: out = (E * Vt^T)/l + V ----
__global__ __launch_bounds__(256) void pv_gemm(const unsigned char* __restrict__ S8,
                                               const unsigned char* __restrict__ Vt8,
                                               const bf16* __restrict__ Vbf,
                                               const float* __restrict__ l,
                                               float* __restrict__ out) {
  __shared__ unsigned char lA[128 * 128];
  __shared__ unsigned char lB[128 * 128];
  const int id = blockIdx.x;
  const int r = id & 7, g = id >> 3;
  const int b = g >> 4;
  const int rem = g & 15;
  const int ty = r * 2 + (rem & 1);
  const int tx = rem >> 1;

  const unsigned char* At = S8 + (size_t)b * 2048 * 2048 + (size_t)ty * 128 * 2048;
  const unsigned char* Bt = Vt8 + (size_t)b * 1024 * 2048 + (size_t)tx * 128 * 2048;
  floatx4 acc[4][4];
  gemm_core_f8(At, Bt, 2048, lA, lB, acc);

  const int tid = threadIdx.x, w = tid >> 6, lane = tid & 63;
  const int subM = (w >> 1) * 64, subN = (w & 1) * 64;
  const int fr = lane & 15, fq = lane >> 4;
  const int rowBase = ty * 128 + subM;
  const int colBase = tx * 128 + subN;
  const float* lb = l + (size_t)b * 2048;
#pragma unroll
  for (int i = 0; i < 4; ++i)
#pragma unroll
    for (int rr = 0; rr < 4; ++rr) {
      int row = rowBase + i * 16 + fq * 4 + rr;
      float inv = 1.0f / lb[row];
#pragma unroll
      for (int j = 0; j < 4; ++j) {
        int col = colBase + j * 16 + fr;
        size_t oi = ((size_t)b * 2048 + row) * 1024 + col;
        out[oi] = acc[i][j][rr] * inv + __bfloat162float(Vbf[oi]);
      }
    }
}

// ---- one cast kernel for x + Wq + Wk + Wv ----
__global__ void cast_all(const float* __restrict__ x, const float* __restrict__ wq,
                         const float* __restrict__ wk, const float* __restrict__ wv,
                         bf16* __restrict__ Xbf, bf16* __restrict__ Wbf) {
  const int blk = blockIdx.x;
  const float* src;
  bf16* dst;
  int base;
  if (blk < 8192)       { src = x;  dst = Xbf;                   base = blk; }
  else if (blk < 9216)  { src = wq; dst = Wbf;                   base = blk - 8192; }
  else if (blk < 10240) { src = wk; dst = Wbf + 1024 * 1024;     base = blk - 9216; }
  else                  { src = wv; dst = Wbf + 2 * 1024 * 1024; base = blk - 10240; }
  int i = base * 256 + threadIdx.x;
  float4 f = ((const float4*)src)[i];
  bf16 tmp[4] = {__float2bfloat16(f.x), __float2bfloat16(f.y),
                 __float2bfloat16(f.z), __float2bfloat16(f.w)};
  ((ushort4*)dst)[i] = *(const ushort4*)tmp;
}

extern "C" void kernel_launch(void* const* d_in, const int* in_sizes, int n_in,
                              void* d_out, int out_size, void* d_ws, size_t ws_size,
                              hipStream_t stream) {
  const float* x  = (const float*)d_in[0];
  const float* Wq = (const float*)d_in[1];
  const float* Wk = (const float*)d_in[2];
  const float* Wv = (const float*)d_in[3];
  float* out = (float*)d_out;

  char* ws = (char*)d_ws;
  bf16* Xbf = (bf16*)ws;           ws += (size_t)8192 * 1024 * 2;      // 16 MB
  bf16* Wbf = (bf16*)ws;           ws += (size_t)3 * 1024 * 1024 * 2;  // 6 MB
  unsigned char* Qf8 = (unsigned char*)ws; ws += (size_t)8192 * 1024;  // 8 MB
  unsigned char* Kf8 = (unsigned char*)ws; ws += (size_t)8192 * 1024;  // 8 MB
  bf16* Vbf = (bf16*)ws;           ws += (size_t)8192 * 1024 * 2;      // 16 MB
  unsigned char* Vt8 = (unsigned char*)ws; ws += (size_t)4 * 1024 * 2048;  // 8 MB
  unsigned char* S8  = (unsigned char*)ws; ws += (size_t)4 * 2048 * 2048;  // 16 MB
  float* l = (float*)ws;           ws += (size_t)8192 * 4;

  hipMemsetAsync(l, 0, 8192 * sizeof(float), stream);
  cast_all<<<11264, 256, 0, stream>>>(x, Wq, Wk, Wv, Xbf, Wbf);
  qkv_gemm<<<1536, 256, 0, stream>>>(Xbf, Wbf, Qf8, Kf8, Vbf);
  transpose_v<<<dim3(32, 16, 4), 256, 0, stream>>>(Vbf, Vt8);
  qk_exp_gemm<<<1024, 256, 0, stream>>>(Qf8, Kf8, S8, l);
  pv_gemm<<<512, 256, 0, stream>>>(S8, Vt8, Vbf, l, out);
}

// Round 5
// 199.525 us; speedup vs baseline: 1.6248x; 1.1291x over previous
//
#include <hip/hip_runtime.h>
#include <hip/hip_bf16.h>

using bf16 = __hip_bfloat16;
typedef __attribute__((ext_vector_type(8))) short short8;   // 8 bf16 = 4 VGPRs
typedef __attribute__((ext_vector_type(4))) float floatx4;  // 4 fp32 acc
typedef __attribute__((ext_vector_type(8))) int int8v;      // 32 fp8 = 8 VGPRs

__device__ __forceinline__ void async_ld16(const void* g, void* l) {
  __builtin_amdgcn_global_load_lds((const __attribute__((address_space(1))) void*)g,
                                   (__attribute__((address_space(3))) void*)l, 16, 0, 0);
}

// HW fp8 conversions (gfx950: OCP e4m3). pk packs 2 floats into 2 bytes of `old`.
__device__ __forceinline__ int pk4_fp8(float a, float b, float c, float d) {
  int v = __builtin_amdgcn_cvt_pk_fp8_f32(a, b, 0, false);
  return __builtin_amdgcn_cvt_pk_fp8_f32(c, d, v, true);  // bytes [a,b,c,d]
}

// ---------------- bf16 128x128 tile core (BK=64), XOR-swizzled LDS ----------------
__device__ __forceinline__ void gemm_core(const bf16* __restrict__ At,
                                          const bf16* __restrict__ Bt,
                                          int K, bf16* lA, bf16* lB,
                                          floatx4 acc[4][4]) {
  const int tid  = threadIdx.x;
  const int w    = tid >> 6;
  const int lane = tid & 63;
  const int subM = (w >> 1) * 64;
  const int subN = (w & 1) * 64;
  const int fr   = lane & 15;
  const int fq   = lane >> 4;

  int srow[4], scol[4], sdst[4];
#pragma unroll
  for (int q = 0; q < 4; ++q) {
    int p = q * 256 + w * 64 + lane;
    int r = p >> 3;
    int j = (p & 7) ^ (r & 7);
    srow[q] = r;
    scol[q] = j * 8;
    sdst[q] = (q * 256 + w * 64) * 8;
  }
  int offA[2][4], offB[2][4];
#pragma unroll
  for (int kc = 0; kc < 2; ++kc)
#pragma unroll
    for (int i = 0; i < 4; ++i) {
      int rA = subM + i * 16 + fr;
      offA[kc][i] = (rA * 8 + ((kc * 4 + fq) ^ (rA & 7))) * 8;
      int rB = subN + i * 16 + fr;
      offB[kc][i] = (rB * 8 + ((kc * 4 + fq) ^ (rB & 7))) * 8;
    }

  floatx4 zero = {0.f, 0.f, 0.f, 0.f};
#pragma unroll
  for (int i = 0; i < 4; ++i)
#pragma unroll
    for (int j = 0; j < 4; ++j) acc[i][j] = zero;

  for (int k0 = 0; k0 < K; k0 += 64) {
    __syncthreads();
#pragma unroll
    for (int q = 0; q < 4; ++q) {
      async_ld16(At + (size_t)srow[q] * K + k0 + scol[q], lA + sdst[q]);
      async_ld16(Bt + (size_t)srow[q] * K + k0 + scol[q], lB + sdst[q]);
    }
    __syncthreads();
#pragma unroll
    for (int kc = 0; kc < 2; ++kc) {
      short8 a[4], b[4];
#pragma unroll
      for (int i = 0; i < 4; ++i) a[i] = *(const short8*)(lA + offA[kc][i]);
#pragma unroll
      for (int j = 0; j < 4; ++j) b[j] = *(const short8*)(lB + offB[kc][j]);
#pragma unroll
      for (int i = 0; i < 4; ++i)
#pragma unroll
        for (int j = 0; j < 4; ++j)
          acc[i][j] = __builtin_amdgcn_mfma_f32_16x16x32_bf16(a[i], b[j], acc[i][j], 0, 0, 0);
    }
  }
}

// ---------------- fp8 (MX-scaled, scales=1.0) 128x128 tile core (BK=128) ----------
__device__ __forceinline__ void gemm_core_f8(const unsigned char* __restrict__ At,
                                             const unsigned char* __restrict__ Bt,
                                             int K, unsigned char* lA, unsigned char* lB,
                                             floatx4 acc[4][4]) {
  const int tid  = threadIdx.x;
  const int w    = tid >> 6;
  const int lane = tid & 63;
  const int subM = (w >> 1) * 64;
  const int subN = (w & 1) * 64;
  const int fr   = lane & 15;
  const int fq   = lane >> 4;

  int srow[4], scol[4], sdst[4];
#pragma unroll
  for (int q = 0; q < 4; ++q) {
    int p = q * 256 + w * 64 + lane;
    int r = p >> 3;
    int j = (p & 7) ^ (r & 7);
    srow[q] = r;
    scol[q] = j * 16;
    sdst[q] = (q * 256 + w * 64) * 16;
  }
  int offA[2][4], offB[2][4];
#pragma unroll
  for (int h = 0; h < 2; ++h)
#pragma unroll
    for (int i = 0; i < 4; ++i) {
      int rA = subM + i * 16 + fr;
      offA[h][i] = rA * 128 + (((fq * 2 + h) ^ (rA & 7)) * 16);
      int rB = subN + i * 16 + fr;
      offB[h][i] = rB * 128 + (((fq * 2 + h) ^ (rB & 7)) * 16);
    }

  floatx4 zero = {0.f, 0.f, 0.f, 0.f};
#pragma unroll
  for (int i = 0; i < 4; ++i)
#pragma unroll
    for (int j = 0; j < 4; ++j) acc[i][j] = zero;

  for (int k0 = 0; k0 < K; k0 += 128) {
    __syncthreads();
#pragma unroll
    for (int q = 0; q < 4; ++q) {
      async_ld16(At + (size_t)srow[q] * K + k0 + scol[q], lA + sdst[q]);
      async_ld16(Bt + (size_t)srow[q] * K + k0 + scol[q], lB + sdst[q]);
    }
    __syncthreads();
    int8v a[4], b[4];
#pragma unroll
    for (int i = 0; i < 4; ++i) {
      int4 lo = *(const int4*)(lA + offA[0][i]);
      int4 hi = *(const int4*)(lA + offA[1][i]);
      int8v v;
      v[0] = lo.x; v[1] = lo.y; v[2] = lo.z; v[3] = lo.w;
      v[4] = hi.x; v[5] = hi.y; v[6] = hi.z; v[7] = hi.w;
      a[i] = v;
    }
#pragma unroll
    for (int j = 0; j < 4; ++j) {
      int4 lo = *(const int4*)(lB + offB[0][j]);
      int4 hi = *(const int4*)(lB + offB[1][j]);
      int8v v;
      v[0] = lo.x; v[1] = lo.y; v[2] = lo.z; v[3] = lo.w;
      v[4] = hi.x; v[5] = hi.y; v[6] = hi.z; v[7] = hi.w;
      b[j] = v;
    }
#pragma unroll
    for (int i = 0; i < 4; ++i)
#pragma unroll
      for (int j = 0; j < 4; ++j)
        acc[i][j] = __builtin_amdgcn_mfma_scale_f32_16x16x128_f8f6f4(
            a[i], b[j], acc[i][j], 0, 0, 0, 0x7F7F7F7F, 0, 0x7F7F7F7F);
  }
}

// ---- V projection (bf16 core): Vbf = Xbf @ Wvbf^T ----
__global__ __launch_bounds__(256) void v_gemm(const bf16* __restrict__ Xbf,
                                              const bf16* __restrict__ Wvbf,
                                              bf16* __restrict__ Vbf) {
  __shared__ bf16 lA[128 * 64];
  __shared__ bf16 lB[128 * 64];
  const int id = blockIdx.x;
  const int r = id & 7, g = id >> 3;
  const int ty = r * 8 + (g & 7);
  const int tx = g >> 3;

  const bf16* At = Xbf + (size_t)ty * 128 * 1024;
  const bf16* Bt = Wvbf + (size_t)tx * 128 * 1024;
  floatx4 acc[4][4];
  gemm_core(At, Bt, 1024, lA, lB, acc);

  const int tid = threadIdx.x, w = tid >> 6, lane = tid & 63;
  const int subM = (w >> 1) * 64, subN = (w & 1) * 64;
  const int fr = lane & 15, fq = lane >> 4;
  const int rowBase = ty * 128 + subM;
  const int colBase = tx * 128 + subN;
#pragma unroll
  for (int i = 0; i < 4; ++i)
#pragma unroll
    for (int j = 0; j < 4; ++j)
#pragma unroll
      for (int rr = 0; rr < 4; ++rr) {
        int row = rowBase + i * 16 + fq * 4 + rr;
        int col = colBase + j * 16 + fr;
        Vbf[(size_t)row * 1024 + col] = __float2bfloat16(acc[i][j][rr]);
      }
}

// ---- Q,K projections (fp8 core): {Q,K}f8 = X8 @ W8[z]^T ----
__global__ __launch_bounds__(256) void qk_proj_gemm(const unsigned char* __restrict__ X8,
                                                    const unsigned char* __restrict__ Wq8,
                                                    const unsigned char* __restrict__ Wk8,
                                                    unsigned char* __restrict__ Qf8,
                                                    unsigned char* __restrict__ Kf8) {
  __shared__ unsigned char lA[128 * 128];
  __shared__ unsigned char lB[128 * 128];
  const int id = blockIdx.x;
  const int r = id & 7, g = id >> 3;
  const int ty = r * 8 + (g & 7);
  const int tx = (g >> 3) & 7;
  const int z = g >> 6;

  const unsigned char* At = X8 + (size_t)ty * 128 * 1024;
  const unsigned char* Bt = (z == 0 ? Wq8 : Wk8) + (size_t)tx * 128 * 1024;
  floatx4 acc[4][4];
  gemm_core_f8(At, Bt, 1024, lA, lB, acc);

  unsigned char* dst = (z == 0) ? Qf8 : Kf8;
  const int tid = threadIdx.x, w = tid >> 6, lane = tid & 63;
  const int subM = (w >> 1) * 64, subN = (w & 1) * 64;
  const int fr = lane & 15, fq = lane >> 4;
  const int rowBase = ty * 128 + subM;
  const int colBase = tx * 128 + subN;
#pragma unroll
  for (int i = 0; i < 4; ++i)
#pragma unroll
    for (int rr = 0; rr < 4; ++rr) {
      int row = rowBase + i * 16 + fq * 4 + rr;
      int p = pk4_fp8(acc[0][0][0] * 0 + acc[i][0][rr], acc[i][1][rr],
                      acc[i][2][rr], acc[i][3][rr]);
#pragma unroll
      for (int j = 0; j < 4; ++j)
        dst[(size_t)row * 1024 + colBase + j * 16 + fr] = (unsigned char)(p >> (8 * j));
    }
}

// ---- V transpose: Vbf[4][2048][1024] bf16 -> Vt8[4][1024][2048] fp8 ----
__global__ __launch_bounds__(256) void transpose_v(const bf16* __restrict__ Vbf,
                                                   unsigned char* __restrict__ Vt8) {
  __shared__ short tile[64][72];
  const int b = blockIdx.z;
  const int s0 = blockIdx.x * 64;
  const int v0 = blockIdx.y * 64;
  const int t = threadIdx.x;
#pragma unroll
  for (int i = 0; i < 2; ++i) {
    int c = t + i * 256;
    int row = c >> 3, cj = c & 7;
    *(short8*)&tile[row][cj * 8] =
        *(const short8*)&Vbf[((size_t)(b * 2048 + s0 + row)) * 1024 + v0 + cj * 8];
  }
  __syncthreads();
  const int vrow = t >> 2, sq = t & 3;
#pragma unroll
  for (int hc = 0; hc < 2; ++hc) {
    float f[8];
#pragma unroll
    for (int e = 0; e < 8; ++e) {
      short s = tile[sq * 16 + hc * 8 + e][vrow];
      f[e] = __bfloat162float(*(bf16*)&s);
    }
    uint2 packed;
    packed.x = (unsigned int)pk4_fp8(f[0], f[1], f[2], f[3]);
    packed.y = (unsigned int)pk4_fp8(f[4], f[5], f[6], f[7]);
    *(uint2*)&Vt8[((size_t)(b * 1024 + v0 + vrow)) * 2048 + s0 + sq * 16 + hc * 8] = packed;
  }
}

// ---- QK^T (fp8 core) + exp fused: E = exp(s/32) fp8; row-sums l ----
__global__ __launch_bounds__(256) void qk_exp_gemm(const unsigned char* __restrict__ Qf8,
                                                   const unsigned char* __restrict__ Kf8,
                                                   unsigned char* __restrict__ S8,
                                                   float* __restrict__ l) {
  __shared__ unsigned char lA[128 * 128];
  __shared__ unsigned char lB[128 * 128];
  const int id = blockIdx.x;
  const int r = id & 7, g = id >> 3;
  const int b = g >> 5;
  const int rem = g & 31;
  const int ty = r * 2 + (rem & 1);
  const int tx = rem >> 1;

  const unsigned char* At = Qf8 + (size_t)b * 2048 * 1024 + (size_t)ty * 128 * 1024;
  const unsigned char* Bt = Kf8 + (size_t)b * 2048 * 1024 + (size_t)tx * 128 * 1024;
  floatx4 acc[4][4];
  gemm_core_f8(At, Bt, 1024, lA, lB, acc);

  const int tid = threadIdx.x, w = tid >> 6, lane = tid & 63;
  const int subM = (w >> 1) * 64, subN = (w & 1) * 64;
  const int fr = lane & 15, fq = lane >> 4;
  const int rowBase = ty * 128 + subM;
  const int colBase = tx * 128 + subN;
  unsigned char* Sb = S8 + (size_t)b * 2048 * 2048;
  float* lb = l + (size_t)b * 2048;
#pragma unroll
  for (int i = 0; i < 4; ++i)
#pragma unroll
    for (int rr = 0; rr < 4; ++rr) {
      int row = rowBase + i * 16 + fq * 4 + rr;
      int p = pk4_fp8(__expf(acc[i][0][rr] * 0.03125f), __expf(acc[i][1][rr] * 0.03125f),
                      __expf(acc[i][2][rr] * 0.03125f), __expf(acc[i][3][rr] * 0.03125f));
      float psum = __builtin_amdgcn_cvt_f32_fp8(p, 0) + __builtin_amdgcn_cvt_f32_fp8(p, 1) +
                   __builtin_amdgcn_cvt_f32_fp8(p, 2) + __builtin_amdgcn_cvt_f32_fp8(p, 3);
#pragma unroll
      for (int j = 0; j < 4; ++j)
        Sb[(size_t)row * 2048 + colBase + j * 16 + fr] = (unsigned char)(p >> (8 * j));
      psum += __shfl_xor(psum, 1, 64);
      psum += __shfl_xor(psum, 2, 64);
      psum += __shfl_xor(psum, 4, 64);
      psum += __shfl_xor(psum, 8, 64);
      if (fr == 0) atomicAdd(&lb[row], psum);
    }
}

// ---- PV (fp8 core) + normalize + residual: out = (E * Vt^T)/l + V ----
__global__ __launch_bounds__(256) void pv_gemm(const unsigned char* __restrict__ S8,
                                               const unsigned char* __restrict__ Vt8,
                                               const bf16* __restrict__ Vbf,
                                               const float* __restrict__ l,
                                               float* __restrict__ out) {
  __shared__ unsigned char lA[128 * 128];
  __shared__ unsigned char lB[128 * 128];
  const int id = blockIdx.x;
  const int r = id & 7, g = id >> 3;
  const int b = g >> 4;
  const int rem = g & 15;
  const int ty = r * 2 + (rem & 1);
  const int tx = rem >> 1;

  const unsigned char* At = S8 + (size_t)b * 2048 * 2048 + (size_t)ty * 128 * 2048;
  const unsigned char* Bt = Vt8 + (size_t)b * 1024 * 2048 + (size_t)tx * 128 * 2048;
  floatx4 acc[4][4];
  gemm_core_f8(At, Bt, 2048, lA, lB, acc);

  const int tid = threadIdx.x, w = tid >> 6, lane = tid & 63;
  const int subM = (w >> 1) * 64, subN = (w & 1) * 64;
  const int fr = lane & 15, fq = lane >> 4;
  const int rowBase = ty * 128 + subM;
  const int colBase = tx * 128 + subN;
  const float* lb = l + (size_t)b * 2048;
#pragma unroll
  for (int i = 0; i < 4; ++i)
#pragma unroll
    for (int rr = 0; rr < 4; ++rr) {
      int row = rowBase + i * 16 + fq * 4 + rr;
      float inv = 1.0f / lb[row];
#pragma unroll
      for (int j = 0; j < 4; ++j) {
        int col = colBase + j * 16 + fr;
        size_t oi = ((size_t)b * 2048 + row) * 1024 + col;
        out[oi] = acc[i][j][rr] * inv + __bfloat162float(Vbf[oi]);
      }
    }
}

// ---- casts: x -> Xbf+X8; wq,wk -> fp8; wv -> bf16; zero l ----
__global__ void cast_all(const float* __restrict__ x, const float* __restrict__ wq,
                         const float* __restrict__ wk, const float* __restrict__ wv,
                         bf16* __restrict__ Xbf, unsigned char* __restrict__ X8,
                         unsigned char* __restrict__ Wq8, unsigned char* __restrict__ Wk8,
                         bf16* __restrict__ Wvbf, float* __restrict__ l) {
  const int blk = blockIdx.x;
  const int t = threadIdx.x;
  if (blk < 8192) {  // x: bf16 + fp8
    int i = blk * 256 + t;
    float4 f = ((const float4*)x)[i];
    bf16 tmp[4] = {__float2bfloat16(f.x), __float2bfloat16(f.y),
                   __float2bfloat16(f.z), __float2bfloat16(f.w)};
    ((ushort4*)Xbf)[i] = *(const ushort4*)tmp;
    ((unsigned int*)X8)[i] = (unsigned int)pk4_fp8(f.x, f.y, f.z, f.w);
  } else if (blk < 10240) {  // wq, wk: fp8 only
    const float* src = (blk < 9216) ? wq : wk;
    unsigned char* dst = (blk < 9216) ? Wq8 : Wk8;
    int i = ((blk - 8192) & 1023) * 256 + t;
    float4 f = ((const float4*)src)[i];
    ((unsigned int*)dst)[i] = (unsigned int)pk4_fp8(f.x, f.y, f.z, f.w);
  } else if (blk < 11264) {  // wv: bf16 only
    int i = (blk - 10240) * 256 + t;
    float4 f = ((const float4*)wv)[i];
    bf16 tmp[4] = {__float2bfloat16(f.x), __float2bfloat16(f.y),
                   __float2bfloat16(f.z), __float2bfloat16(f.w)};
    ((ushort4*)Wvbf)[i] = *(const ushort4*)tmp;
  } else {  // zero l (8 blocks x 1024 floats)
    int i = (blk - 11264) * 256 + t;
    ((float4*)l)[i] = make_float4(0.f, 0.f, 0.f, 0.f);
  }
}

extern "C" void kernel_launch(void* const* d_in, const int* in_sizes, int n_in,
                              void* d_out, int out_size, void* d_ws, size_t ws_size,
                              hipStream_t stream) {
  const float* x  = (const float*)d_in[0];
  const float* Wq = (const float*)d_in[1];
  const float* Wk = (const float*)d_in[2];
  const float* Wv = (const float*)d_in[3];
  float* out = (float*)d_out;

  char* ws = (char*)d_ws;
  bf16* Xbf = (bf16*)ws;                   ws += (size_t)8192 * 1024 * 2;   // 16 MB
  unsigned char* X8 = (unsigned char*)ws;  ws += (size_t)8192 * 1024;       // 8 MB
  unsigned char* Wq8 = (unsigned char*)ws; ws += (size_t)1024 * 1024;       // 1 MB
  unsigned char* Wk8 = (unsigned char*)ws; ws += (size_t)1024 * 1024;       // 1 MB
  bf16* Wvbf = (bf16*)ws;                  ws += (size_t)1024 * 1024 * 2;   // 2 MB
  unsigned char* Qf8 = (unsigned char*)ws; ws += (size_t)8192 * 1024;       // 8 MB
  unsigned char* Kf8 = (unsigned char*)ws; ws += (size_t)8192 * 1024;       // 8 MB
  bf16* Vbf = (bf16*)ws;                   ws += (size_t)8192 * 1024 * 2;   // 16 MB
  unsigned char* Vt8 = (unsigned char*)ws; ws += (size_t)4 * 1024 * 2048;   // 8 MB
  unsigned char* S8  = (unsigned char*)ws; ws += (size_t)4 * 2048 * 2048;   // 16 MB
  float* l = (float*)ws;                   ws += (size_t)8192 * 4;

  cast_all<<<11272, 256, 0, stream>>>(x, Wq, Wk, Wv, Xbf, X8, Wq8, Wk8, Wvbf, l);
  v_gemm<<<512, 256, 0, stream>>>(Xbf, Wvbf, Vbf);
  qk_proj_gemm<<<1024, 256, 0, stream>>>(X8, Wq8, Wk8, Qf8, Kf8);
  transpose_v<<<dim3(32, 16, 4), 256, 0, stream>>>(Vbf, Vt8);
  qk_exp_gemm<<<1024, 256, 0, stream>>>(Qf8, Kf8, S8, l);
  pv_gemm<<<512, 256, 0, stream>>>(S8, Vt8, Vbf, l, out);
}

// Round 6
// 188.110 us; speedup vs baseline: 1.7234x; 1.0607x over previous
//
#include <hip/hip_runtime.h>
#include <hip/hip_bf16.h>

using bf16 = __hip_bfloat16;
typedef __attribute__((ext_vector_type(8))) short short8;   // 8 bf16 = 4 VGPRs
typedef __attribute__((ext_vector_type(4))) float floatx4;  // 4 fp32 acc
typedef __attribute__((ext_vector_type(8))) int int8v;      // 32 fp8 = 8 VGPRs

__device__ __forceinline__ void async_ld16(const void* g, void* l) {
  __builtin_amdgcn_global_load_lds((const __attribute__((address_space(1))) void*)g,
                                   (__attribute__((address_space(3))) void*)l, 16, 0, 0);
}

// HW fp8 conversions (gfx950: OCP e4m3).
__device__ __forceinline__ int pk4_fp8(float a, float b, float c, float d) {
  int v = __builtin_amdgcn_cvt_pk_fp8_f32(a, b, 0, false);
  return __builtin_amdgcn_cvt_pk_fp8_f32(c, d, v, true);  // bytes [a,b,c,d]
}

// k-order permutation: within each 64-byte k-group, byte position f*4+j holds
// original k-index j*16+f (f in [0,16), j in [0,4)). Applied consistently to
// {Qf8,Kf8} (k=d) and {S8,Vt8} (k=s) -> GEMM results are exactly unchanged,
// but MFMA C-fragment epilogues store one aligned u32 per (i,rr) instead of
// 16 scattered byte stores.

// ---------------- bf16 128x128 tile core (BK=64), XOR-swizzled LDS ----------------
__device__ __forceinline__ void gemm_core(const bf16* __restrict__ At,
                                          const bf16* __restrict__ Bt,
                                          int K, bf16* lA, bf16* lB,
                                          floatx4 acc[4][4]) {
  const int tid  = threadIdx.x;
  const int w    = tid >> 6;
  const int lane = tid & 63;
  const int subM = (w >> 1) * 64;
  const int subN = (w & 1) * 64;
  const int fr   = lane & 15;
  const int fq   = lane >> 4;

  int srow[4], scol[4], sdst[4];
#pragma unroll
  for (int q = 0; q < 4; ++q) {
    int p = q * 256 + w * 64 + lane;
    int r = p >> 3;
    int j = (p & 7) ^ (r & 7);
    srow[q] = r;
    scol[q] = j * 8;
    sdst[q] = (q * 256 + w * 64) * 8;
  }
  int offA[2][4], offB[2][4];
#pragma unroll
  for (int kc = 0; kc < 2; ++kc)
#pragma unroll
    for (int i = 0; i < 4; ++i) {
      int rA = subM + i * 16 + fr;
      offA[kc][i] = (rA * 8 + ((kc * 4 + fq) ^ (rA & 7))) * 8;
      int rB = subN + i * 16 + fr;
      offB[kc][i] = (rB * 8 + ((kc * 4 + fq) ^ (rB & 7))) * 8;
    }

  floatx4 zero = {0.f, 0.f, 0.f, 0.f};
#pragma unroll
  for (int i = 0; i < 4; ++i)
#pragma unroll
    for (int j = 0; j < 4; ++j) acc[i][j] = zero;

  for (int k0 = 0; k0 < K; k0 += 64) {
    __syncthreads();
#pragma unroll
    for (int q = 0; q < 4; ++q) {
      async_ld16(At + (size_t)srow[q] * K + k0 + scol[q], lA + sdst[q]);
      async_ld16(Bt + (size_t)srow[q] * K + k0 + scol[q], lB + sdst[q]);
    }
    __syncthreads();
#pragma unroll
    for (int kc = 0; kc < 2; ++kc) {
      short8 a[4], b[4];
#pragma unroll
      for (int i = 0; i < 4; ++i) a[i] = *(const short8*)(lA + offA[kc][i]);
#pragma unroll
      for (int j = 0; j < 4; ++j) b[j] = *(const short8*)(lB + offB[kc][j]);
#pragma unroll
      for (int i = 0; i < 4; ++i)
#pragma unroll
        for (int j = 0; j < 4; ++j)
          acc[i][j] = __builtin_amdgcn_mfma_f32_16x16x32_bf16(a[i], b[j], acc[i][j], 0, 0, 0);
    }
  }
}

// ---------------- fp8 (MX-scaled, scales=1.0) 128x128 tile core (BK=128) ----------
__device__ __forceinline__ void gemm_core_f8(const unsigned char* __restrict__ At,
                                             const unsigned char* __restrict__ Bt,
                                             int K, unsigned char* lA, unsigned char* lB,
                                             floatx4 acc[4][4]) {
  const int tid  = threadIdx.x;
  const int w    = tid >> 6;
  const int lane = tid & 63;
  const int subM = (w >> 1) * 64;
  const int subN = (w & 1) * 64;
  const int fr   = lane & 15;
  const int fq   = lane >> 4;

  int srow[4], scol[4], sdst[4];
#pragma unroll
  for (int q = 0; q < 4; ++q) {
    int p = q * 256 + w * 64 + lane;
    int r = p >> 3;
    int j = (p & 7) ^ (r & 7);
    srow[q] = r;
    scol[q] = j * 16;
    sdst[q] = (q * 256 + w * 64) * 16;
  }
  int offA[2][4], offB[2][4];
#pragma unroll
  for (int h = 0; h < 2; ++h)
#pragma unroll
    for (int i = 0; i < 4; ++i) {
      int rA = subM + i * 16 + fr;
      offA[h][i] = rA * 128 + (((fq * 2 + h) ^ (rA & 7)) * 16);
      int rB = subN + i * 16 + fr;
      offB[h][i] = rB * 128 + (((fq * 2 + h) ^ (rB & 7)) * 16);
    }

  floatx4 zero = {0.f, 0.f, 0.f, 0.f};
#pragma unroll
  for (int i = 0; i < 4; ++i)
#pragma unroll
    for (int j = 0; j < 4; ++j) acc[i][j] = zero;

  for (int k0 = 0; k0 < K; k0 += 128) {
    __syncthreads();
#pragma unroll
    for (int q = 0; q < 4; ++q) {
      async_ld16(At + (size_t)srow[q] * K + k0 + scol[q], lA + sdst[q]);
      async_ld16(Bt + (size_t)srow[q] * K + k0 + scol[q], lB + sdst[q]);
    }
    __syncthreads();
    int8v a[4], b[4];
#pragma unroll
    for (int i = 0; i < 4; ++i) {
      int4 lo = *(const int4*)(lA + offA[0][i]);
      int4 hi = *(const int4*)(lA + offA[1][i]);
      int8v v;
      v[0] = lo.x; v[1] = lo.y; v[2] = lo.z; v[3] = lo.w;
      v[4] = hi.x; v[5] = hi.y; v[6] = hi.z; v[7] = hi.w;
      a[i] = v;
    }
#pragma unroll
    for (int j = 0; j < 4; ++j) {
      int4 lo = *(const int4*)(lB + offB[0][j]);
      int4 hi = *(const int4*)(lB + offB[1][j]);
      int8v v;
      v[0] = lo.x; v[1] = lo.y; v[2] = lo.z; v[3] = lo.w;
      v[4] = hi.x; v[5] = hi.y; v[6] = hi.z; v[7] = hi.w;
      b[j] = v;
    }
#pragma unroll
    for (int i = 0; i < 4; ++i)
#pragma unroll
      for (int j = 0; j < 4; ++j)
        acc[i][j] = __builtin_amdgcn_mfma_scale_f32_16x16x128_f8f6f4(
            a[i], b[j], acc[i][j], 0, 0, 0, 0x7F7F7F7F, 0, 0x7F7F7F7F);
  }
}

// ---- merged projections: blocks [0,512) = V (bf16); [512,1536) = Q,K (fp8) ----
__global__ __launch_bounds__(256) void proj_gemm(
    const bf16* __restrict__ Xbf, const bf16* __restrict__ Wvbf, bf16* __restrict__ Vbf,
    const unsigned char* __restrict__ X8, const unsigned char* __restrict__ Wq8,
    const unsigned char* __restrict__ Wk8,
    unsigned char* __restrict__ Qf8, unsigned char* __restrict__ Kf8) {
  __shared__ __align__(16) char lds[32768];
  const int id = blockIdx.x;
  const int tid = threadIdx.x, w = tid >> 6, lane = tid & 63;
  const int subM = (w >> 1) * 64, subN = (w & 1) * 64;
  const int fr = lane & 15, fq = lane >> 4;

  if (id < 512) {  // V projection, bf16 core
    const int r = id & 7, g = id >> 3;
    const int ty = r * 8 + (g & 7), tx = g >> 3;
    bf16* lA = (bf16*)lds;
    bf16* lB = (bf16*)(lds + 16384);
    floatx4 acc[4][4];
    gemm_core(Xbf + (size_t)ty * 128 * 1024, Wvbf + (size_t)tx * 128 * 1024,
              1024, lA, lB, acc);
    const int rowBase = ty * 128 + subM;
    const int colBase = tx * 128 + subN;
#pragma unroll
    for (int i = 0; i < 4; ++i)
#pragma unroll
      for (int j = 0; j < 4; ++j)
#pragma unroll
        for (int rr = 0; rr < 4; ++rr) {
          int row = rowBase + i * 16 + fq * 4 + rr;
          int col = colBase + j * 16 + fr;
          Vbf[(size_t)row * 1024 + col] = __float2bfloat16(acc[i][j][rr]);
        }
  } else {  // Q/K projections, fp8 core, pi-permuted output (k=d)
    const int local = id - 512;
    const int z = local >> 9, lid = local & 511;
    const int r = lid & 7, g = lid >> 3;
    const int ty = r * 8 + (g & 7), tx = g >> 3;
    unsigned char* lA = (unsigned char*)lds;
    unsigned char* lB = (unsigned char*)(lds + 16384);
    floatx4 acc[4][4];
    gemm_core_f8(X8 + (size_t)ty * 128 * 1024,
                 (z == 0 ? Wq8 : Wk8) + (size_t)tx * 128 * 1024, 1024, lA, lB, acc);
    unsigned char* dst = (z == 0) ? Qf8 : Kf8;
    const int rowBase = ty * 128 + subM;
    const int colBase = tx * 128 + subN;
#pragma unroll
    for (int i = 0; i < 4; ++i)
#pragma unroll
      for (int rr = 0; rr < 4; ++rr) {
        int row = rowBase + i * 16 + fq * 4 + rr;
        unsigned int p = (unsigned int)pk4_fp8(acc[i][0][rr], acc[i][1][rr],
                                               acc[i][2][rr], acc[i][3][rr]);
        *(unsigned int*)&dst[(size_t)row * 1024 + colBase + fr * 4] = p;
      }
  }
}

// ---- merged: blocks [0,1024) = QK^T+exp (fp8); [1024,3072) = V transpose ----
__global__ __launch_bounds__(256) void mid_kernel(
    const unsigned char* __restrict__ Qf8, const unsigned char* __restrict__ Kf8,
    unsigned char* __restrict__ S8, float* __restrict__ l,
    const bf16* __restrict__ Vbf, unsigned char* __restrict__ Vt8) {
  __shared__ __align__(16) char lds[32768];
  const int id = blockIdx.x;
  const int t = threadIdx.x;

  if (id < 1024) {  // QK^T + exp, pi-permuted output (k=s)
    const int r = id & 7, g = id >> 3;
    const int b = g >> 5;
    const int rem = g & 31;
    const int ty = r * 2 + (rem & 1);
    const int tx = rem >> 1;
    unsigned char* lA = (unsigned char*)lds;
    unsigned char* lB = (unsigned char*)(lds + 16384);
    floatx4 acc[4][4];
    gemm_core_f8(Qf8 + (size_t)b * 2048 * 1024 + (size_t)ty * 128 * 1024,
                 Kf8 + (size_t)b * 2048 * 1024 + (size_t)tx * 128 * 1024,
                 1024, lA, lB, acc);
    const int w = t >> 6, lane = t & 63;
    const int subM = (w >> 1) * 64, subN = (w & 1) * 64;
    const int fr = lane & 15, fq = lane >> 4;
    const int rowBase = ty * 128 + subM;
    const int colBase = tx * 128 + subN;
    unsigned char* Sb = S8 + (size_t)b * 2048 * 2048;
    float* lb = l + (size_t)b * 2048;
#pragma unroll
    for (int i = 0; i < 4; ++i)
#pragma unroll
      for (int rr = 0; rr < 4; ++rr) {
        int row = rowBase + i * 16 + fq * 4 + rr;
        unsigned int p = (unsigned int)pk4_fp8(
            __expf(acc[i][0][rr] * 0.03125f), __expf(acc[i][1][rr] * 0.03125f),
            __expf(acc[i][2][rr] * 0.03125f), __expf(acc[i][3][rr] * 0.03125f));
        *(unsigned int*)&Sb[(size_t)row * 2048 + colBase + fr * 4] = p;
        float psum = __builtin_amdgcn_cvt_f32_fp8(p, 0) + __builtin_amdgcn_cvt_f32_fp8(p, 1) +
                     __builtin_amdgcn_cvt_f32_fp8(p, 2) + __builtin_amdgcn_cvt_f32_fp8(p, 3);
        psum += __shfl_xor(psum, 1, 64);
        psum += __shfl_xor(psum, 2, 64);
        psum += __shfl_xor(psum, 4, 64);
        psum += __shfl_xor(psum, 8, 64);
        if (fr == 0) atomicAdd(&lb[row], psum);
      }
  } else {  // V transpose: Vbf[b][s][v] -> Vt8[b][v][pi(s)]
    const int t2 = id - 1024;
    const int b = t2 >> 9, rem = t2 & 511;
    const int xs = rem & 31, yv = rem >> 5;
    const int s0 = xs * 64, v0 = yv * 64;
    short(*tile)[72] = (short(*)[72])lds;
#pragma unroll
    for (int i = 0; i < 2; ++i) {
      int c = t + i * 256;
      int row = c >> 3, cj = c & 7;
      *(short8*)&tile[row][cj * 8] =
          *(const short8*)&Vbf[((size_t)(b * 2048 + s0 + row)) * 1024 + v0 + cj * 8];
    }
    __syncthreads();
    const int vrow = t >> 2, sq = t & 3;
#pragma unroll
    for (int hc = 0; hc < 2; ++hc) {
      float f[8];
#pragma unroll
      for (int e = 0; e < 8; ++e) {
        int p = sq * 16 + hc * 8 + e;       // output byte position within 64-group
        int s = (p & 3) * 16 + (p >> 2);    // inverse-pi: original s offset
        short sh = tile[s][vrow];
        f[e] = __bfloat162float(*(bf16*)&sh);
      }
      uint2 packed;
      packed.x = (unsigned int)pk4_fp8(f[0], f[1], f[2], f[3]);
      packed.y = (unsigned int)pk4_fp8(f[4], f[5], f[6], f[7]);
      *(uint2*)&Vt8[((size_t)(b * 1024 + v0 + vrow)) * 2048 + s0 + sq * 16 + hc * 8] = packed;
    }
  }
}

// ---- PV (fp8 core) + normalize + residual: out = (E * Vt^T)/l + V ----
__global__ __launch_bounds__(256) void pv_gemm(const unsigned char* __restrict__ S8,
                                               const unsigned char* __restrict__ Vt8,
                                               const bf16* __restrict__ Vbf,
                                               const float* __restrict__ l,
                                               float* __restrict__ out) {
  __shared__ __align__(16) char lds[32768];
  unsigned char* lA = (unsigned char*)lds;
  unsigned char* lB = (unsigned char*)(lds + 16384);
  const int id = blockIdx.x;
  const int r = id & 7, g = id >> 3;
  const int b = g >> 4;
  const int rem = g & 15;
  const int ty = r * 2 + (rem & 1);
  const int tx = rem >> 1;

  floatx4 acc[4][4];
  gemm_core_f8(S8 + (size_t)b * 2048 * 2048 + (size_t)ty * 128 * 2048,
               Vt8 + (size_t)b * 1024 * 2048 + (size_t)tx * 128 * 2048,
               2048, lA, lB, acc);

  const int tid = threadIdx.x, w = tid >> 6, lane = tid & 63;
  const int subM = (w >> 1) * 64, subN = (w & 1) * 64;
  const int fr = lane & 15, fq = lane >> 4;
  const int rowBase = ty * 128 + subM;
  const int colBase = tx * 128 + subN;
  const float* lb = l + (size_t)b * 2048;
#pragma unroll
  for (int i = 0; i < 4; ++i)
#pragma unroll
    for (int rr = 0; rr < 4; ++rr) {
      int row = rowBase + i * 16 + fq * 4 + rr;
      float inv = 1.0f / lb[row];
#pragma unroll
      for (int j = 0; j < 4; ++j) {
        int col = colBase + j * 16 + fr;
        size_t oi = ((size_t)b * 2048 + row) * 1024 + col;
        out[oi] = acc[i][j][rr] * inv + __bfloat162float(Vbf[oi]);
      }
    }
}

// ---- casts: x -> Xbf+X8; wq,wk -> fp8; wv -> bf16; zero l ----
__global__ void cast_all(const float* __restrict__ x, const float* __restrict__ wq,
                         const float* __restrict__ wk, const float* __restrict__ wv,
                         bf16* __restrict__ Xbf, unsigned char* __restrict__ X8,
                         unsigned char* __restrict__ Wq8, unsigned char* __restrict__ Wk8,
                         bf16* __restrict__ Wvbf, float* __restrict__ l) {
  const int blk = blockIdx.x;
  const int t = threadIdx.x;
  if (blk < 8192) {  // x: bf16 + fp8
    int i = blk * 256 + t;
    float4 f = ((const float4*)x)[i];
    bf16 tmp[4] = {__float2bfloat16(f.x), __float2bfloat16(f.y),
                   __float2bfloat16(f.z), __float2bfloat16(f.w)};
    ((ushort4*)Xbf)[i] = *(const ushort4*)tmp;
    ((unsigned int*)X8)[i] = (unsigned int)pk4_fp8(f.x, f.y, f.z, f.w);
  } else if (blk < 10240) {  // wq, wk: fp8 only
    const float* src = (blk < 9216) ? wq : wk;
    unsigned char* dst = (blk < 9216) ? Wq8 : Wk8;
    int i = ((blk - 8192) & 1023) * 256 + t;
    float4 f = ((const float4*)src)[i];
    ((unsigned int*)dst)[i] = (unsigned int)pk4_fp8(f.x, f.y, f.z, f.w);
  } else if (blk < 11264) {  // wv: bf16 only
    int i = (blk - 10240) * 256 + t;
    float4 f = ((const float4*)wv)[i];
    bf16 tmp[4] = {__float2bfloat16(f.x), __float2bfloat16(f.y),
                   __float2bfloat16(f.z), __float2bfloat16(f.w)};
    ((ushort4*)Wvbf)[i] = *(const ushort4*)tmp;
  } else {  // zero l
    int i = (blk - 11264) * 256 + t;
    ((float4*)l)[i] = make_float4(0.f, 0.f, 0.f, 0.f);
  }
}

extern "C" void kernel_launch(void* const* d_in, const int* in_sizes, int n_in,
                              void* d_out, int out_size, void* d_ws, size_t ws_size,
                              hipStream_t stream) {
  const float* x  = (const float*)d_in[0];
  const float* Wq = (const float*)d_in[1];
  const float* Wk = (const float*)d_in[2];
  const float* Wv = (const float*)d_in[3];
  float* out = (float*)d_out;

  char* ws = (char*)d_ws;
  bf16* Xbf = (bf16*)ws;                   ws += (size_t)8192 * 1024 * 2;   // 16 MB
  unsigned char* X8 = (unsigned char*)ws;  ws += (size_t)8192 * 1024;       // 8 MB
  unsigned char* Wq8 = (unsigned char*)ws; ws += (size_t)1024 * 1024;       // 1 MB
  unsigned char* Wk8 = (unsigned char*)ws; ws += (size_t)1024 * 1024;       // 1 MB
  bf16* Wvbf = (bf16*)ws;                  ws += (size_t)1024 * 1024 * 2;   // 2 MB
  unsigned char* Qf8 = (unsigned char*)ws; ws += (size_t)8192 * 1024;       // 8 MB
  unsigned char* Kf8 = (unsigned char*)ws; ws += (size_t)8192 * 1024;       // 8 MB
  bf16* Vbf = (bf16*)ws;                   ws += (size_t)8192 * 1024 * 2;   // 16 MB
  unsigned char* Vt8 = (unsigned char*)ws; ws += (size_t)4 * 1024 * 2048;   // 8 MB
  unsigned char* S8  = (unsigned char*)ws; ws += (size_t)4 * 2048 * 2048;   // 16 MB
  float* l = (float*)ws;                   ws += (size_t)8192 * 4;

  cast_all<<<11272, 256, 0, stream>>>(x, Wq, Wk, Wv, Xbf, X8, Wq8, Wk8, Wvbf, l);
  proj_gemm<<<1536, 256, 0, stream>>>(Xbf, Wvbf, Vbf, X8, Wq8, Wk8, Qf8, Kf8);
  mid_kernel<<<3072, 256, 0, stream>>>(Qf8, Kf8, S8, l, Vbf, Vt8);
  pv_gemm<<<512, 256, 0, stream>>>(S8, Vt8, Vbf, l, out);
}

// Round 7
// 176.277 us; speedup vs baseline: 1.8390x; 1.0671x over previous
//
#include <hip/hip_runtime.h>
#include <hip/hip_bf16.h>

using bf16 = __hip_bfloat16;
typedef __attribute__((ext_vector_type(8))) short short8;   // 8 bf16 = 4 VGPRs
typedef __attribute__((ext_vector_type(4))) float floatx4;  // 4 fp32 acc
typedef __attribute__((ext_vector_type(8))) int int8v;      // 32 fp8 = 8 VGPRs

__device__ __forceinline__ void async_ld16(const void* g, void* l) {
  __builtin_amdgcn_global_load_lds((const __attribute__((address_space(1))) void*)g,
                                   (__attribute__((address_space(3))) void*)l, 16, 0, 0);
}

__device__ __forceinline__ int pk4_fp8(float a, float b, float c, float d) {
  int v = __builtin_amdgcn_cvt_pk_fp8_f32(a, b, 0, false);
  return __builtin_amdgcn_cvt_pk_fp8_f32(c, d, v, true);  // bytes [a,b,c,d]
}

__device__ __forceinline__ int8v ld_frag16(const unsigned char* lo, const unsigned char* hi) {
  int4 l0 = *(const int4*)lo, h0 = *(const int4*)hi;
  int8v v;
  v[0] = l0.x; v[1] = l0.y; v[2] = l0.z; v[3] = l0.w;
  v[4] = h0.x; v[5] = h0.y; v[6] = h0.z; v[7] = h0.w;
  return v;
}

// Swizzle: chunk j of row r stored at position j ^ (r&7) ^ ((r&8)>>1).
// The r&8 term puts rows fr and fr+8 (same 16-lane read phase) 16 banks apart.

// ---------------- bf16 128x128 tile core (BK=64) — unchanged (0 conflicts) ----------
__device__ __forceinline__ void gemm_core(const bf16* __restrict__ At,
                                          const bf16* __restrict__ Bt,
                                          int K, bf16* lA, bf16* lB,
                                          floatx4 acc[4][4]) {
  const int tid  = threadIdx.x;
  const int w    = tid >> 6;
  const int lane = tid & 63;
  const int subM = (w >> 1) * 64;
  const int subN = (w & 1) * 64;
  const int fr   = lane & 15;
  const int fq   = lane >> 4;

  int srow[4], scol[4], sdst[4];
#pragma unroll
  for (int q = 0; q < 4; ++q) {
    int p = q * 256 + w * 64 + lane;
    int r = p >> 3;
    int j = (p & 7) ^ (r & 7);
    srow[q] = r;
    scol[q] = j * 8;
    sdst[q] = (q * 256 + w * 64) * 8;
  }
  int offA[2][4], offB[2][4];
#pragma unroll
  for (int kc = 0; kc < 2; ++kc)
#pragma unroll
    for (int i = 0; i < 4; ++i) {
      int rA = subM + i * 16 + fr;
      offA[kc][i] = (rA * 8 + ((kc * 4 + fq) ^ (rA & 7))) * 8;
      int rB = subN + i * 16 + fr;
      offB[kc][i] = (rB * 8 + ((kc * 4 + fq) ^ (rB & 7))) * 8;
    }

  floatx4 zero = {0.f, 0.f, 0.f, 0.f};
#pragma unroll
  for (int i = 0; i < 4; ++i)
#pragma unroll
    for (int j = 0; j < 4; ++j) acc[i][j] = zero;

  for (int k0 = 0; k0 < K; k0 += 64) {
    __syncthreads();
#pragma unroll
    for (int q = 0; q < 4; ++q) {
      async_ld16(At + (size_t)srow[q] * K + k0 + scol[q], lA + sdst[q]);
      async_ld16(Bt + (size_t)srow[q] * K + k0 + scol[q], lB + sdst[q]);
    }
    __syncthreads();
#pragma unroll
    for (int kc = 0; kc < 2; ++kc) {
      short8 a[4], b[4];
#pragma unroll
      for (int i = 0; i < 4; ++i) a[i] = *(const short8*)(lA + offA[kc][i]);
#pragma unroll
      for (int j = 0; j < 4; ++j) b[j] = *(const short8*)(lB + offB[kc][j]);
#pragma unroll
      for (int i = 0; i < 4; ++i)
#pragma unroll
        for (int j = 0; j < 4; ++j)
          acc[i][j] = __builtin_amdgcn_mfma_f32_16x16x32_bf16(a[i], b[j], acc[i][j], 0, 0, 0);
    }
  }
}

// ---------------- fp8 128x128 tile core (BK=128), improved swizzle (pv) ------------
__device__ __forceinline__ void gemm_core_f8(const unsigned char* __restrict__ At,
                                             const unsigned char* __restrict__ Bt,
                                             int K, unsigned char* lA, unsigned char* lB,
                                             floatx4 acc[4][4]) {
  const int tid  = threadIdx.x;
  const int w    = tid >> 6;
  const int lane = tid & 63;
  const int subM = (w >> 1) * 64;
  const int subN = (w & 1) * 64;
  const int fr   = lane & 15;
  const int fq   = lane >> 4;

  int srow[4], scol[4], sdst[4];
#pragma unroll
  for (int q = 0; q < 4; ++q) {
    int p = q * 256 + w * 64 + lane;
    int r = p >> 3;
    int j = (p & 7) ^ (r & 7) ^ ((r & 8) >> 1);
    srow[q] = r;
    scol[q] = j * 16;
    sdst[q] = (q * 256 + w * 64) * 16;
  }
  int offA[2][4], offB[2][4];
#pragma unroll
  for (int h = 0; h < 2; ++h)
#pragma unroll
    for (int i = 0; i < 4; ++i) {
      int rA = subM + i * 16 + fr;
      offA[h][i] = rA * 128 + (((fq * 2 + h) ^ (rA & 7) ^ ((rA & 8) >> 1)) * 16);
      int rB = subN + i * 16 + fr;
      offB[h][i] = rB * 128 + (((fq * 2 + h) ^ (rB & 7) ^ ((rB & 8) >> 1)) * 16);
    }

  floatx4 zero = {0.f, 0.f, 0.f, 0.f};
#pragma unroll
  for (int i = 0; i < 4; ++i)
#pragma unroll
    for (int j = 0; j < 4; ++j) acc[i][j] = zero;

  for (int k0 = 0; k0 < K; k0 += 128) {
    __syncthreads();
#pragma unroll
    for (int q = 0; q < 4; ++q) {
      async_ld16(At + (size_t)srow[q] * K + k0 + scol[q], lA + sdst[q]);
      async_ld16(Bt + (size_t)srow[q] * K + k0 + scol[q], lB + sdst[q]);
    }
    __syncthreads();
    int8v a[4], b[4];
#pragma unroll
    for (int i = 0; i < 4; ++i) a[i] = ld_frag16(lA + offA[0][i], lA + offA[1][i]);
#pragma unroll
    for (int j = 0; j < 4; ++j) b[j] = ld_frag16(lB + offB[0][j], lB + offB[1][j]);
#pragma unroll
    for (int i = 0; i < 4; ++i)
#pragma unroll
      for (int j = 0; j < 4; ++j)
        acc[i][j] = __builtin_amdgcn_mfma_scale_f32_16x16x128_f8f6f4(
            a[i], b[j], acc[i][j], 0, 0, 0, 0x7F7F7F7F, 0, 0x7F7F7F7F);
  }
}

// ------------- fp8 v2 core: block 128x256, wave tile 64x128, BK=128 ----------------
// LDS:MFMA cycle ratio ~1.04 (vs 1.4 for 128x128): 2x MFMA per A-fragment byte.
__device__ __forceinline__ void gemm_core_f8_v2(const unsigned char* __restrict__ At,
                                                const unsigned char* __restrict__ Bt,
                                                int K, unsigned char* lA, unsigned char* lB,
                                                floatx4 acc[4][8]) {
  const int tid  = threadIdx.x;
  const int w    = tid >> 6;
  const int lane = tid & 63;
  const int subM = (w >> 1) * 64;
  const int subN = (w & 1) * 128;
  const int fr   = lane & 15;
  const int fq   = lane >> 4;

  // staging: A 1024 chunks (128 rows), B 2048 chunks (256 rows)
  int srowA[4], scolA[4], sdstA[4];
#pragma unroll
  for (int q = 0; q < 4; ++q) {
    int p = q * 256 + w * 64 + lane;
    int r = p >> 3;
    int j = (p & 7) ^ (r & 7) ^ ((r & 8) >> 1);
    srowA[q] = r; scolA[q] = j * 16; sdstA[q] = (q * 256 + w * 64) * 16;
  }
  int srowB[8], scolB[8], sdstB[8];
#pragma unroll
  for (int q = 0; q < 8; ++q) {
    int p = q * 256 + w * 64 + lane;
    int r = p >> 3;
    int j = (p & 7) ^ (r & 7) ^ ((r & 8) >> 1);
    srowB[q] = r; scolB[q] = j * 16; sdstB[q] = (q * 256 + w * 64) * 16;
  }
  int offA[2][4], offB[2][8];
#pragma unroll
  for (int h = 0; h < 2; ++h) {
#pragma unroll
    for (int i = 0; i < 4; ++i) {
      int rA = subM + i * 16 + fr;
      offA[h][i] = rA * 128 + (((fq * 2 + h) ^ (rA & 7) ^ ((rA & 8) >> 1)) * 16);
    }
#pragma unroll
    for (int j = 0; j < 8; ++j) {
      int rB = subN + j * 16 + fr;
      offB[h][j] = rB * 128 + (((fq * 2 + h) ^ (rB & 7) ^ ((rB & 8) >> 1)) * 16);
    }
  }

  floatx4 zero = {0.f, 0.f, 0.f, 0.f};
#pragma unroll
  for (int i = 0; i < 4; ++i)
#pragma unroll
    for (int j = 0; j < 8; ++j) acc[i][j] = zero;

  for (int k0 = 0; k0 < K; k0 += 128) {
    __syncthreads();
#pragma unroll
    for (int q = 0; q < 4; ++q)
      async_ld16(At + (size_t)srowA[q] * K + k0 + scolA[q], lA + sdstA[q]);
#pragma unroll
    for (int q = 0; q < 8; ++q)
      async_ld16(Bt + (size_t)srowB[q] * K + k0 + scolB[q], lB + sdstB[q]);
    __syncthreads();
    int8v a[4];
#pragma unroll
    for (int i = 0; i < 4; ++i) a[i] = ld_frag16(lA + offA[0][i], lA + offA[1][i]);
#pragma unroll
    for (int j = 0; j < 8; ++j) {
      int8v bf = ld_frag16(lB + offB[0][j], lB + offB[1][j]);
#pragma unroll
      for (int i = 0; i < 4; ++i)
        acc[i][j] = __builtin_amdgcn_mfma_scale_f32_16x16x128_f8f6f4(
            a[i], bf, acc[i][j], 0, 0, 0, 0x7F7F7F7F, 0, 0x7F7F7F7F);
    }
  }
}

// ---- merged projections: blocks [0,512) = V (bf16 128x128); [512,1024) = Q,K (fp8 v2) ----
__global__ __launch_bounds__(256, 2) void proj_gemm(
    const bf16* __restrict__ Xbf, const bf16* __restrict__ Wvbf, bf16* __restrict__ Vbf,
    const unsigned char* __restrict__ X8, const unsigned char* __restrict__ Wq8,
    const unsigned char* __restrict__ Wk8,
    unsigned char* __restrict__ Qf8, unsigned char* __restrict__ Kf8) {
  __shared__ __align__(16) char lds[49152];
  const int id = blockIdx.x;
  const int tid = threadIdx.x, w = tid >> 6, lane = tid & 63;
  const int fr = lane & 15, fq = lane >> 4;

  if (id < 512) {  // V projection, bf16 core
    const int r = id & 7, g = id >> 3;
    const int ty = r * 8 + (g & 7), tx = g >> 3;
    bf16* lA = (bf16*)lds;
    bf16* lB = (bf16*)(lds + 16384);
    floatx4 acc[4][4];
    gemm_core(Xbf + (size_t)ty * 128 * 1024, Wvbf + (size_t)tx * 128 * 1024,
              1024, lA, lB, acc);
    const int subM = (w >> 1) * 64, subN = (w & 1) * 64;
    const int rowBase = ty * 128 + subM;
    const int colBase = tx * 128 + subN;
#pragma unroll
    for (int i = 0; i < 4; ++i)
#pragma unroll
      for (int j = 0; j < 4; ++j)
#pragma unroll
        for (int rr = 0; rr < 4; ++rr) {
          int row = rowBase + i * 16 + fq * 4 + rr;
          int col = colBase + j * 16 + fr;
          Vbf[(size_t)row * 1024 + col] = __float2bfloat16(acc[i][j][rr]);
        }
  } else {  // Q/K projections, fp8 v2 core (block 128x256), pi-permuted output (k=d)
    const int local = id - 512;
    const int z = local >> 8, lid = local & 255;
    const int r = lid & 7, g = lid >> 3;       // g in [0,32)
    const int ty = r * 8 + (g & 7);            // M-tiles: 64
    const int tx = g >> 3;                     // N-tiles: 4 (256 cols each)
    unsigned char* lA = (unsigned char*)lds;
    unsigned char* lB = (unsigned char*)(lds + 16384);
    floatx4 acc[4][8];
    gemm_core_f8_v2(X8 + (size_t)ty * 128 * 1024,
                    (z == 0 ? Wq8 : Wk8) + (size_t)tx * 256 * 1024, 1024, lA, lB, acc);
    unsigned char* dst = (z == 0) ? Qf8 : Kf8;
    const int subM = (w >> 1) * 64, subN = (w & 1) * 128;
    const int rowBase = ty * 128 + subM;
    const int colBase = tx * 256 + subN;
#pragma unroll
    for (int i = 0; i < 4; ++i)
#pragma unroll
      for (int rr = 0; rr < 4; ++rr) {
        int row = rowBase + i * 16 + fq * 4 + rr;
        unsigned int p0 = (unsigned int)pk4_fp8(acc[i][0][rr], acc[i][1][rr],
                                                acc[i][2][rr], acc[i][3][rr]);
        unsigned int p1 = (unsigned int)pk4_fp8(acc[i][4][rr], acc[i][5][rr],
                                                acc[i][6][rr], acc[i][7][rr]);
        *(unsigned int*)&dst[(size_t)row * 1024 + colBase + fr * 4] = p0;
        *(unsigned int*)&dst[(size_t)row * 1024 + colBase + 64 + fr * 4] = p1;
      }
  }
}

// ---- merged: blocks [0,512) = QK^T+exp (fp8 v2); [512,2560) = V transpose ----
__global__ __launch_bounds__(256, 2) void mid_kernel(
    const unsigned char* __restrict__ Qf8, const unsigned char* __restrict__ Kf8,
    unsigned char* __restrict__ S8, float* __restrict__ l,
    const bf16* __restrict__ Vbf, unsigned char* __restrict__ Vt8) {
  __shared__ __align__(16) char lds[49152];
  const int id = blockIdx.x;
  const int t = threadIdx.x;

  if (id < 512) {  // QK^T + exp, pi-permuted output (k=s)
    const int r = id & 7, g = id >> 3;          // g in [0,64)
    const int b = g >> 4;
    const int rem = g & 15;
    const int ty = r * 2 + (rem & 1);           // M-tiles 16
    const int tx = rem >> 1;                    // N-tiles 8 (256 cols)
    unsigned char* lA = (unsigned char*)lds;
    unsigned char* lB = (unsigned char*)(lds + 16384);
    floatx4 acc[4][8];
    gemm_core_f8_v2(Qf8 + (size_t)b * 2048 * 1024 + (size_t)ty * 128 * 1024,
                    Kf8 + (size_t)b * 2048 * 1024 + (size_t)tx * 256 * 1024,
                    1024, lA, lB, acc);
    const int w = t >> 6, lane = t & 63;
    const int subM = (w >> 1) * 64, subN = (w & 1) * 128;
    const int fr = lane & 15, fq = lane >> 4;
    const int rowBase = ty * 128 + subM;
    const int colBase = tx * 256 + subN;
    unsigned char* Sb = S8 + (size_t)b * 2048 * 2048;
    float* lb = l + (size_t)b * 2048;
#pragma unroll
    for (int i = 0; i < 4; ++i)
#pragma unroll
      for (int rr = 0; rr < 4; ++rr) {
        int row = rowBase + i * 16 + fq * 4 + rr;
        unsigned int p0 = (unsigned int)pk4_fp8(
            __expf(acc[i][0][rr] * 0.03125f), __expf(acc[i][1][rr] * 0.03125f),
            __expf(acc[i][2][rr] * 0.03125f), __expf(acc[i][3][rr] * 0.03125f));
        unsigned int p1 = (unsigned int)pk4_fp8(
            __expf(acc[i][4][rr] * 0.03125f), __expf(acc[i][5][rr] * 0.03125f),
            __expf(acc[i][6][rr] * 0.03125f), __expf(acc[i][7][rr] * 0.03125f));
        *(unsigned int*)&Sb[(size_t)row * 2048 + colBase + fr * 4] = p0;
        *(unsigned int*)&Sb[(size_t)row * 2048 + colBase + 64 + fr * 4] = p1;
        float psum = __builtin_amdgcn_cvt_f32_fp8(p0, 0) + __builtin_amdgcn_cvt_f32_fp8(p0, 1) +
                     __builtin_amdgcn_cvt_f32_fp8(p0, 2) + __builtin_amdgcn_cvt_f32_fp8(p0, 3) +
                     __builtin_amdgcn_cvt_f32_fp8(p1, 0) + __builtin_amdgcn_cvt_f32_fp8(p1, 1) +
                     __builtin_amdgcn_cvt_f32_fp8(p1, 2) + __builtin_amdgcn_cvt_f32_fp8(p1, 3);
        psum += __shfl_xor(psum, 1, 64);
        psum += __shfl_xor(psum, 2, 64);
        psum += __shfl_xor(psum, 4, 64);
        psum += __shfl_xor(psum, 8, 64);
        if (fr == 0) atomicAdd(&lb[row], psum);
      }
  } else {  // V transpose: Vbf[b][s][v] -> Vt8[b][v][pi(s)]
    const int t2 = id - 512;
    const int b = t2 >> 9, rem = t2 & 511;
    const int xs = rem & 31, yv = rem >> 5;
    const int s0 = xs * 64, v0 = yv * 64;
    short(*tile)[72] = (short(*)[72])lds;
#pragma unroll
    for (int i = 0; i < 2; ++i) {
      int c = t + i * 256;
      int row = c >> 3, cj = c & 7;
      *(short8*)&tile[row][cj * 8] =
          *(const short8*)&Vbf[((size_t)(b * 2048 + s0 + row)) * 1024 + v0 + cj * 8];
    }
    __syncthreads();
    const int vrow = t >> 2, sq = t & 3;
#pragma unroll
    for (int hc = 0; hc < 2; ++hc) {
      float f[8];
#pragma unroll
      for (int e = 0; e < 8; ++e) {
        int p = sq * 16 + hc * 8 + e;       // output byte position within 64-group
        int s = (p & 3) * 16 + (p >> 2);    // inverse-pi: original s offset
        short sh = tile[s][vrow];
        f[e] = __bfloat162float(*(bf16*)&sh);
      }
      uint2 packed;
      packed.x = (unsigned int)pk4_fp8(f[0], f[1], f[2], f[3]);
      packed.y = (unsigned int)pk4_fp8(f[4], f[5], f[6], f[7]);
      *(uint2*)&Vt8[((size_t)(b * 1024 + v0 + vrow)) * 2048 + s0 + sq * 16 + hc * 8] = packed;
    }
  }
}

// ---- PV (fp8 128x128 core) + normalize + residual: out = (E * Vt^T)/l + V ----
__global__ __launch_bounds__(256) void pv_gemm(const unsigned char* __restrict__ S8,
                                               const unsigned char* __restrict__ Vt8,
                                               const bf16* __restrict__ Vbf,
                                               const float* __restrict__ l,
                                               float* __restrict__ out) {
  __shared__ __align__(16) char lds[32768];
  unsigned char* lA = (unsigned char*)lds;
  unsigned char* lB = (unsigned char*)(lds + 16384);
  const int id = blockIdx.x;
  const int r = id & 7, g = id >> 3;
  const int b = g >> 4;
  const int rem = g & 15;
  const int ty = r * 2 + (rem & 1);
  const int tx = rem >> 1;

  floatx4 acc[4][4];
  gemm_core_f8(S8 + (size_t)b * 2048 * 2048 + (size_t)ty * 128 * 2048,
               Vt8 + (size_t)b * 1024 * 2048 + (size_t)tx * 128 * 2048,
               2048, lA, lB, acc);

  const int tid = threadIdx.x, w = tid >> 6, lane = tid & 63;
  const int subM = (w >> 1) * 64, subN = (w & 1) * 64;
  const int fr = lane & 15, fq = lane >> 4;
  const int rowBase = ty * 128 + subM;
  const int colBase = tx * 128 + subN;
  const float* lb = l + (size_t)b * 2048;
#pragma unroll
  for (int i = 0; i < 4; ++i)
#pragma unroll
    for (int rr = 0; rr < 4; ++rr) {
      int row = rowBase + i * 16 + fq * 4 + rr;
      float inv = 1.0f / lb[row];
#pragma unroll
      for (int j = 0; j < 4; ++j) {
        int col = colBase + j * 16 + fr;
        size_t oi = ((size_t)b * 2048 + row) * 1024 + col;
        out[oi] = acc[i][j][rr] * inv + __bfloat162float(Vbf[oi]);
      }
    }
}

// ---- casts: x -> Xbf+X8; wq,wk -> fp8; wv -> bf16; zero l ----
__global__ void cast_all(const float* __restrict__ x, const float* __restrict__ wq,
                         const float* __restrict__ wk, const float* __restrict__ wv,
                         bf16* __restrict__ Xbf, unsigned char* __restrict__ X8,
                         unsigned char* __restrict__ Wq8, unsigned char* __restrict__ Wk8,
                         bf16* __restrict__ Wvbf, float* __restrict__ l) {
  const int blk = blockIdx.x;
  const int t = threadIdx.x;
  if (blk < 8192) {  // x: bf16 + fp8
    int i = blk * 256 + t;
    float4 f = ((const float4*)x)[i];
    bf16 tmp[4] = {__float2bfloat16(f.x), __float2bfloat16(f.y),
                   __float2bfloat16(f.z), __float2bfloat16(f.w)};
    ((ushort4*)Xbf)[i] = *(const ushort4*)tmp;
    ((unsigned int*)X8)[i] = (unsigned int)pk4_fp8(f.x, f.y, f.z, f.w);
  } else if (blk < 10240) {  // wq, wk: fp8 only
    const float* src = (blk < 9216) ? wq : wk;
    unsigned char* dst = (blk < 9216) ? Wq8 : Wk8;
    int i = ((blk - 8192) & 1023) * 256 + t;
    float4 f = ((const float4*)src)[i];
    ((unsigned int*)dst)[i] = (unsigned int)pk4_fp8(f.x, f.y, f.z, f.w);
  } else if (blk < 11264) {  // wv: bf16 only
    int i = (blk - 10240) * 256 + t;
    float4 f = ((const float4*)wv)[i];
    bf16 tmp[4] = {__float2bfloat16(f.x), __float2bfloat16(f.y),
                   __float2bfloat16(f.z), __float2bfloat16(f.w)};
    ((ushort4*)Wvbf)[i] = *(const ushort4*)tmp;
  } else {  // zero l
    int i = (blk - 11264) * 256 + t;
    ((float4*)l)[i] = make_float4(0.f, 0.f, 0.f, 0.f);
  }
}

extern "C" void kernel_launch(void* const* d_in, const int* in_sizes, int n_in,
                              void* d_out, int out_size, void* d_ws, size_t ws_size,
                              hipStream_t stream) {
  const float* x  = (const float*)d_in[0];
  const float* Wq = (const float*)d_in[1];
  const float* Wk = (const float*)d_in[2];
  const float* Wv = (const float*)d_in[3];
  float* out = (float*)d_out;

  char* ws = (char*)d_ws;
  bf16* Xbf = (bf16*)ws;                   ws += (size_t)8192 * 1024 * 2;   // 16 MB
  unsigned char* X8 = (unsigned char*)ws;  ws += (size_t)8192 * 1024;       // 8 MB
  unsigned char* Wq8 = (unsigned char*)ws; ws += (size_t)1024 * 1024;       // 1 MB
  unsigned char* Wk8 = (unsigned char*)ws; ws += (size_t)1024 * 1024;       // 1 MB
  bf16* Wvbf = (bf16*)ws;                  ws += (size_t)1024 * 1024 * 2;   // 2 MB
  unsigned char* Qf8 = (unsigned char*)ws; ws += (size_t)8192 * 1024;       // 8 MB
  unsigned char* Kf8 = (unsigned char*)ws; ws += (size_t)8192 * 1024;       // 8 MB
  bf16* Vbf = (bf16*)ws;                   ws += (size_t)8192 * 1024 * 2;   // 16 MB
  unsigned char* Vt8 = (unsigned char*)ws; ws += (size_t)4 * 1024 * 2048;   // 8 MB
  unsigned char* S8  = (unsigned char*)ws; ws += (size_t)4 * 2048 * 2048;   // 16 MB
  float* l = (float*)ws;                   ws += (size_t)8192 * 4;

  cast_all<<<11272, 256, 0, stream>>>(x, Wq, Wk, Wv, Xbf, X8, Wq8, Wk8, Wvbf, l);
  proj_gemm<<<1024, 256, 0, stream>>>(Xbf, Wvbf, Vbf, X8, Wq8, Wk8, Qf8, Kf8);
  mid_kernel<<<2560, 256, 0, stream>>>(Qf8, Kf8, S8, l, Vbf, Vt8);
  pv_gemm<<<512, 256, 0, stream>>>(S8, Vt8, Vbf, l, out);
}